// Round 11
// baseline (574.697 us; speedup 1.0000x reference)
//
#include <hip/hip_runtime.h>
#include <hip/hip_bf16.h>
#include <cstdint>

#define DEV __device__ __forceinline__

typedef __bf16 bf16_t;
typedef __bf16 bf16x8 __attribute__((ext_vector_type(8)));
typedef __bf16 bf16x4 __attribute__((ext_vector_type(4)));
typedef float  f32x4  __attribute__((ext_vector_type(4)));

constexpr int Bb = 2, Ss = 2048, Dd = 1024, Hh = 16, DKk = 64, FFf = 4096;
constexpr int TOK = Bb * Ss;          // 4096 tokens
constexpr float LN_EPS = 1e-6f;

// ---- async global->LDS, 16B per lane (wave-uniform base + lane*16) ----
DEV void g2l16(const void* g, void* l) {
    __builtin_amdgcn_global_load_lds(
        (const __attribute__((address_space(1))) unsigned int*)g,
        (__attribute__((address_space(3))) unsigned int*)l, 16, 0, 0);
}

#define WAITCNT(N) asm volatile("s_waitcnt vmcnt(" #N ")" ::: "memory")
#define SCHEDB() __builtin_amdgcn_sched_barrier(0)

// ==========  ALL weights fp32 [K,N] -> bf16 [N,K] + bias concat, one launch =
__global__ __launch_bounds__(256)
void transpose_all(const float* __restrict__ wq, const float* __restrict__ wk,
                   const float* __restrict__ wv, const float* __restrict__ wo,
                   const float* __restrict__ wi0, const float* __restrict__ wi1,
                   const float* __restrict__ wff,
                   bf16_t* wqT, bf16_t* wkT, bf16_t* wvT, bf16_t* woT,
                   bf16_t* wi0T, bf16_t* wi1T, bf16_t* wffT,
                   const float* __restrict__ bq, const float* __restrict__ bk,
                   const float* __restrict__ bv, float* __restrict__ cb) {
    __shared__ float t[32][33];
    const int id = blockIdx.x;
    if (id == 16384) {      // bias concat block
        const int tid = threadIdx.x;
#pragma unroll
        for (int i = 0; i < 4; ++i) {
            const int j = i * 256 + tid;
            cb[j] = bq[j]; cb[1024 + j] = bk[j]; cb[2048 + j] = bv[j];
        }
        return;
    }
    const float* src; bf16_t* dst; int K, N, tt;
    if (id < 4096) {
        const int w = id >> 10; tt = id & 1023; K = 1024; N = 1024;
        src = w == 0 ? wq : w == 1 ? wk : w == 2 ? wv : wo;
        dst = w == 0 ? wqT : w == 1 ? wkT : w == 2 ? wvT : woT;
    } else if (id < 12288) {
        const int w = (id - 4096) >> 12; tt = (id - 4096) & 4095; K = 1024; N = 4096;
        src = w ? wi1 : wi0; dst = w ? wi1T : wi0T;
    } else {
        tt = id - 12288; K = 4096; N = 1024;
        src = wff; dst = wffT;
    }
    const int ntn = N >> 5;
    const int n0 = (tt % ntn) * 32, k0 = (tt / ntn) * 32;
    const int tx = threadIdx.x & 31, ty = threadIdx.x >> 5;
#pragma unroll
    for (int i = 0; i < 4; ++i)
        t[ty + 8 * i][tx] = src[(size_t)(k0 + ty + 8 * i) * N + n0 + tx];
    __syncthreads();
#pragma unroll
    for (int i = 0; i < 4; ++i)
        dst[(size_t)(n0 + ty + 8 * i) * K + k0 + tx] = (bf16_t)t[tx][ty + 8 * i];
}

// =====================  LayerNorm fp32 -> bf16  =====================
__global__ __launch_bounds__(256)
void ln_fwd(const float* __restrict__ x, const float* __restrict__ g,
            const float* __restrict__ b, bf16_t* __restrict__ out) {
    __shared__ float red[8];
    const int row = blockIdx.x, tid = threadIdx.x;
    const float4 v = ((const float4*)(x + (size_t)row * Dd))[tid];
    float s  = v.x + v.y + v.z + v.w;
    float sq = v.x * v.x + v.y * v.y + v.z * v.z + v.w * v.w;
#pragma unroll
    for (int o = 32; o; o >>= 1) { s += __shfl_xor(s, o); sq += __shfl_xor(sq, o); }
    if ((tid & 63) == 0) { red[tid >> 6] = s; red[4 + (tid >> 6)] = sq; }
    __syncthreads();
    s  = red[0] + red[1] + red[2] + red[3];
    sq = red[4] + red[5] + red[6] + red[7];
    const float mean = s * (1.f / Dd);
    const float var  = sq * (1.f / Dd) - mean * mean;
    const float rs   = rsqrtf(var + LN_EPS);
    const float4 gv = ((const float4*)g)[tid];
    const float4 bv = ((const float4*)b)[tid];
    bf16x4 o4;
    o4[0] = (bf16_t)((v.x - mean) * rs * gv.x + bv.x);
    o4[1] = (bf16_t)((v.y - mean) * rs * gv.y + bv.y);
    o4[2] = (bf16_t)((v.z - mean) * rs * gv.z + bv.z);
    o4[3] = (bf16_t)((v.w - mean) * rs * gv.w + bv.w);
    ((bf16x4*)(out + (size_t)row * Dd))[tid] = o4;
}

// ---- shared GEMM epilogue ----
template <int EPI>
DEV void gemm_epi(float val, int gr, int gc, int N, size_t zofs,
                  void* outp, void* out2, void* out3, const float* resid) {
    if constexpr (EPI == 0) {
        ((bf16_t*)outp)[(size_t)gr * N + gc] = (bf16_t)val;
    } else if constexpr (EPI == 1) {
        const size_t idx = (size_t)gr * N + gc;
        ((float*)outp)[idx] = val + resid[idx];
    } else if constexpr (EPI == 4) {
        ((float*)outp)[zofs + (size_t)gr * N + gc] = val;   // split-K partial
    } else {
        const int sel = gc >> 10, col = gc & 1023;
        if (sel == 0) {
            ((bf16_t*)outp)[(size_t)gr * 1024 + col] = (bf16_t)val;
        } else if (sel == 1) {
            ((bf16_t*)out2)[(size_t)gr * 1024 + col] = (bf16_t)val;
        } else {
            const int bb = gr >> 11, sS = gr & 2047;
            ((bf16_t*)out3)[((size_t)bb << 21) + ((size_t)col << 11) + sS] = (bf16_t)val;
        }
    }
}

// =====================  GEMM: C = A[M,ld] @ Bt[N,ld]^T + bias  ==============
template <int BM, int BN, int EPI>
__global__ __launch_bounds__(256)
void gemm_t(const bf16_t* __restrict__ A, const bf16_t* __restrict__ Bt,
            const float* __restrict__ bias, const float* __restrict__ resid,
            void* __restrict__ outp, void* __restrict__ out2,
            void* __restrict__ out3, int M, int N, int K, int ld) {
    constexpr int WM = BM / 2, WN = BN / 2;
    constexpr int MI = WM / 16, NI = WN / 16;
    constexpr int CA = BM / 32, CB = BN / 32;
    __shared__ bf16_t As[BM * 64];
    __shared__ bf16_t Bs[BN * 64];
    const int tid = threadIdx.x;
    const int lane = tid & 63;
    const int wave = tid >> 6;
    const int wr = wave >> 1, wc = wave & 1;
    const int m0 = blockIdx.y * BM, n0 = blockIdx.x * BN;
    const int koff = blockIdx.z * K;
    const size_t zofs = (size_t)blockIdx.z * M * N;
    const int lr = lane & 15, lg = lane >> 4;

    const f32x4 z0 = {0.f, 0.f, 0.f, 0.f};
    f32x4 acc[MI][NI];
#pragma unroll
    for (int i = 0; i < MI; ++i)
#pragma unroll
        for (int j = 0; j < NI; ++j) acc[i][j] = z0;

    for (int k0 = 0; k0 < K; k0 += 64) {
#pragma unroll
        for (int c = 0; c < CA; ++c) {
            const int lin = c * 256 + tid;
            const int row = lin >> 3, col = (lin & 7) * 8;
            g2l16(A + (size_t)(m0 + row) * ld + koff + k0 + col, (char*)As + lin * 16);
        }
#pragma unroll
        for (int c = 0; c < CB; ++c) {
            const int lin = c * 256 + tid;
            const int row = lin >> 3, col = (lin & 7) * 8;
            g2l16(Bt + (size_t)(n0 + row) * ld + koff + k0 + col, (char*)Bs + lin * 16);
        }
        __syncthreads();

        bf16x8 af[2][MI], bw[2][NI];
#pragma unroll
        for (int kk = 0; kk < 2; ++kk)
#pragma unroll
            for (int mi = 0; mi < MI; ++mi)
                af[kk][mi] = *(const bf16x8*)(As + (wr * WM + mi * 16 + lr) * 64 +
                                              kk * 32 + lg * 8);
#pragma unroll
        for (int kk = 0; kk < 2; ++kk)
#pragma unroll
            for (int ni = 0; ni < NI; ++ni)
                bw[kk][ni] = *(const bf16x8*)(Bs + (wc * WN + ni * 16 + lr) * 64 +
                                              kk * 32 + lg * 8);
#pragma unroll
        for (int mi = 0; mi < MI; ++mi)
#pragma unroll
            for (int ni = 0; ni < NI; ++ni) {
                acc[mi][ni] = __builtin_amdgcn_mfma_f32_16x16x32_bf16(
                    af[0][mi], bw[0][ni], acc[mi][ni], 0, 0, 0);
                acc[mi][ni] = __builtin_amdgcn_mfma_f32_16x16x32_bf16(
                    af[1][mi], bw[1][ni], acc[mi][ni], 0, 0, 0);
            }
        __syncthreads();
    }

#pragma unroll
    for (int mi = 0; mi < MI; ++mi)
#pragma unroll
        for (int ni = 0; ni < NI; ++ni) {
            const int gc = n0 + wc * WN + ni * 16 + lr;
            const int gr0 = m0 + wr * WM + mi * 16 + lg * 4;
            const float bvl = (EPI == 4) ? 0.f : bias[gc];
#pragma unroll
            for (int r = 0; r < 4; ++r)
                gemm_epi<EPI>(acc[mi][ni][r] + bvl, gr0 + r, gc, N, zofs,
                              outp, out2, out3, resid);
        }
}

// =====================  split-K=2 reduce: out = p0+p1+bff+h1  =================
__global__ __launch_bounds__(256)
void reduce2(const float* __restrict__ part, const float* __restrict__ h1,
             const float* __restrict__ bff, float* __restrict__ out) {
    const int row = blockIdx.x, tid = threadIdx.x;
    const size_t idx = (size_t)row * 1024 + tid * 4;
    const float4 a = *(const float4*)(part + idx);
    const float4 b = *(const float4*)(part + (size_t)4096 * 1024 + idx);
    const float4 r = *(const float4*)(h1 + idx);
    const float4 bv = *(const float4*)(bff + tid * 4);
    float4 o;
    o.x = a.x + b.x + r.x + bv.x;
    o.y = a.y + b.y + r.y + bv.y;
    o.z = a.z + b.z + r.z + bv.z;
    o.w = a.w + b.w + r.w + bv.w;
    *(float4*)(out + idx) = o;
}

// =====================  fused FFN-up + GeGLU (unchanged)  ====================
__global__ __launch_bounds__(256)
void gemm_geglu(const bf16_t* __restrict__ A, const bf16_t* __restrict__ Bg,
                const bf16_t* __restrict__ Bl, const float* __restrict__ bi0,
                const float* __restrict__ bi1, bf16_t* __restrict__ gout) {
    __shared__ bf16_t As[128 * 64];
    __shared__ bf16_t Bgs[64 * 64];
    __shared__ bf16_t Bls[64 * 64];
    const int tid = threadIdx.x;
    const int lane = tid & 63;
    const int wave = tid >> 6;
    const int wr = wave >> 1, wc = wave & 1;
    const int m0 = blockIdx.y * 128, n0 = blockIdx.x * 64;
    const int lr = lane & 15, lg = lane >> 4;

    const f32x4 z0 = {0.f, 0.f, 0.f, 0.f};
    f32x4 ag[4][2], al[4][2];
#pragma unroll
    for (int i = 0; i < 4; ++i)
#pragma unroll
        for (int j = 0; j < 2; ++j) { ag[i][j] = z0; al[i][j] = z0; }

    for (int k0 = 0; k0 < 1024; k0 += 64) {
#pragma unroll
        for (int c = 0; c < 4; ++c) {
            const int lin = c * 256 + tid;
            const int row = lin >> 3, col = (lin & 7) * 8;
            g2l16(A + (size_t)(m0 + row) * 1024 + k0 + col, (char*)As + lin * 16);
        }
#pragma unroll
        for (int c = 0; c < 2; ++c) {
            const int lin = c * 256 + tid;
            const int row = lin >> 3, col = (lin & 7) * 8;
            g2l16(Bg + (size_t)(n0 + row) * 1024 + k0 + col, (char*)Bgs + lin * 16);
        }
#pragma unroll
        for (int c = 0; c < 2; ++c) {
            const int lin = c * 256 + tid;
            const int row = lin >> 3, col = (lin & 7) * 8;
            g2l16(Bl + (size_t)(n0 + row) * 1024 + k0 + col, (char*)Bls + lin * 16);
        }
        __syncthreads();

        bf16x8 af[2][4], bg[2][2], bl[2][2];
#pragma unroll
        for (int kk = 0; kk < 2; ++kk) {
#pragma unroll
            for (int mi = 0; mi < 4; ++mi)
                af[kk][mi] = *(const bf16x8*)(As + (wr * 64 + mi * 16 + lr) * 64 +
                                              kk * 32 + lg * 8);
#pragma unroll
            for (int ni = 0; ni < 2; ++ni) {
                bg[kk][ni] = *(const bf16x8*)(Bgs + (wc * 32 + ni * 16 + lr) * 64 +
                                              kk * 32 + lg * 8);
                bl[kk][ni] = *(const bf16x8*)(Bls + (wc * 32 + ni * 16 + lr) * 64 +
                                              kk * 32 + lg * 8);
            }
        }
#pragma unroll
        for (int mi = 0; mi < 4; ++mi)
#pragma unroll
            for (int ni = 0; ni < 2; ++ni) {
#pragma unroll
                for (int kk = 0; kk < 2; ++kk) {
                    ag[mi][ni] = __builtin_amdgcn_mfma_f32_16x16x32_bf16(
                        af[kk][mi], bg[kk][ni], ag[mi][ni], 0, 0, 0);
                    al[mi][ni] = __builtin_amdgcn_mfma_f32_16x16x32_bf16(
                        af[kk][mi], bl[kk][ni], al[mi][ni], 0, 0, 0);
                }
            }
        __syncthreads();
    }

#pragma unroll
    for (int mi = 0; mi < 4; ++mi)
#pragma unroll
        for (int ni = 0; ni < 2; ++ni) {
            const int gc = n0 + wc * 32 + ni * 16 + lr;
            const int gr0 = m0 + wr * 64 + mi * 16 + lg * 4;
            const float b0 = bi0[gc], b1 = bi1[gc];
#pragma unroll
            for (int r = 0; r < 4; ++r) {
                const float x = ag[mi][ni][r] + b0;
                const float y = al[mi][ni][r] + b1;
                const float ge = 0.5f * x * (1.f + erff(x * 0.70710678118654752f));
                gout[(size_t)(gr0 + r) * 4096 + gc] = (bf16_t)(ge * y);
            }
        }
}

// ======  fused attention v7.2: round-9 schedule + NONTEMPORAL attn stores ===
// Block = (bh, 128 q-rows), 8 waves. K/V 64x64 tiles staged via one g2l16 per
// wave per tile; triple buffer, raw s_barrier + counted vmcnt. attn written
// with nt stores (bypass L2) so K/V stay L2-resident across pass B.
__global__ __launch_bounds__(512)
void attn_fused(const bf16_t* __restrict__ q, const bf16_t* __restrict__ k,
                const bf16_t* __restrict__ vT, float* __restrict__ attn,
                bf16_t* __restrict__ ctx) {
    __shared__ bf16_t Ks[3][64 * 64];
    __shared__ bf16_t Vs[3][64 * 64];
    const int tid = threadIdx.x, lane = tid & 63, wave = tid >> 6;   // 8 waves
    const int lr = lane & 15, lg = lane >> 4;
    int blk = blockIdx.x;
    blk = (blk & 7) * 64 + (blk >> 3);       // XCD swizzle (512 % 8 == 0)
    const int qc = blk & 15, bh = blk >> 4;
    const int b = bh >> 4, h = bh & 15;
    const int q0 = qc * 128 + wave * 16;
    const size_t base = (size_t)b * (Ss * 1024) + h * 64;
    constexpr float SCL = 0.125f * 1.4426950408889634f;   // 1/sqrt(64) * log2(e)
    const f32x4 z0 = {0.f, 0.f, 0.f, 0.f};

    const int st_r8 = lane >> 3;
    const int st_row = wave * 8 + st_r8;
    const int st_c0 = (lane & 7) ^ (st_r8 & 3) ^ ((wave & 1) << 2);

    const bf16x8 aq0 = *(const bf16x8*)(q + base + (size_t)(q0 + lr) * 1024 + lg * 8);
    const bf16x8 aq1 = *(const bf16x8*)(q + base + (size_t)(q0 + lr) * 1024 + 32 + lg * 8);
    const bf16_t* kb = k + base;
    const bf16_t* vb_base = vT + ((size_t)bh * 64) * Ss;

#define STAGE_K(kt_, buf_)                                                       \
    g2l16(kb + (size_t)((kt_) * 64 + st_row) * 1024 + st_c0 * 8,                 \
          &Ks[buf_][wave * 512]);
#define STAGE_V(kt_, buf_)                                                       \
    g2l16(vb_base + (size_t)st_row * Ss + (kt_) * 64 + st_c0 * 8,                \
          &Vs[buf_][wave * 512]);

    // ---- pass A: esum ----
    f32x4 ea = z0, eb = z0;
    STAGE_K(0, 0);
    STAGE_K(1, 1);
    for (int kt = 0; kt < 32; ++kt) {
        const int buf = kt % 3;
        if (kt == 31) { WAITCNT(0); } else { WAITCNT(1); }
        SCHEDB();
        __builtin_amdgcn_s_barrier();
        SCHEDB();
        f32x4 sa[4];
        __builtin_amdgcn_s_setprio(1);
#pragma unroll
        for (int ct = 0; ct < 4; ++ct) {
            const int ar = ct * 16 + lr;
            const int hz = (ar & 3) | (((ar >> 3) & 1) << 2);
            bf16x8 k0 = *(const bf16x8*)&Ks[buf][ar * 64 + (lg ^ hz) * 8];
            bf16x8 k1 = *(const bf16x8*)&Ks[buf][ar * 64 + (((4 + lg) ^ hz)) * 8];
            sa[ct] = __builtin_amdgcn_mfma_f32_16x16x32_bf16(k0, aq0, z0, 0, 0, 0);
            sa[ct] = __builtin_amdgcn_mfma_f32_16x16x32_bf16(k1, aq1, sa[ct], 0, 0, 0);
        }
        __builtin_amdgcn_s_setprio(0);
#pragma unroll
        for (int r = 0; r < 4; ++r) {
            ea[r] += exp2f(sa[0][r] * SCL) + exp2f(sa[1][r] * SCL);
            eb[r] += exp2f(sa[2][r] * SCL) + exp2f(sa[3][r] * SCL);
        }
        if (kt + 2 < 32) STAGE_K(kt + 2, (kt + 2) % 3);
    }
    float e = ((ea[0] + ea[1]) + (ea[2] + ea[3])) + ((eb[0] + eb[1]) + (eb[2] + eb[3]));
    e += __shfl_xor(e, 16);
    e += __shfl_xor(e, 32);
    const float invl = 1.f / e;

    f32x4 cacc[4];
#pragma unroll
    for (int nd = 0; nd < 4; ++nd) cacc[nd] = z0;

    float* attn_base = attn + ((size_t)bh * Ss + q0 + lr) * Ss;

    __builtin_amdgcn_s_barrier();   // all waves done reading pass-A buffers
    SCHEDB();

    // ---- pass B ----
    STAGE_K(0, 0); STAGE_V(0, 0);
    STAGE_K(1, 1); STAGE_V(1, 1);
    for (int kt = 0; kt < 32; ++kt) {
        const int buf = kt % 3;
        if (kt == 0) { WAITCNT(2); }
        else if (kt == 31) { WAITCNT(4); }
        else { WAITCNT(6); }
        SCHEDB();
        __builtin_amdgcn_s_barrier();
        SCHEDB();
#pragma unroll
        for (int kp = 0; kp < 2; ++kp) {
            bf16x8 pa;
            __builtin_amdgcn_s_setprio(1);
#pragma unroll
            for (int ch = 0; ch < 2; ++ch) {
                const int pr = kp * 32 + (lr >> 2) * 8 + ch * 4 + (lr & 3);
                const int hz = (pr & 3) | (((pr >> 3) & 1) << 2);
                bf16x8 k0 = *(const bf16x8*)&Ks[buf][pr * 64 + (lg ^ hz) * 8];
                bf16x8 k1 = *(const bf16x8*)&Ks[buf][pr * 64 + (((4 + lg) ^ hz)) * 8];
                f32x4 sb = __builtin_amdgcn_mfma_f32_16x16x32_bf16(k0, aq0, z0, 0, 0, 0);
                sb = __builtin_amdgcn_mfma_f32_16x16x32_bf16(k1, aq1, sb, 0, 0, 0);
                f32x4 p;
                p[0] = exp2f(sb[0] * SCL) * invl;
                p[1] = exp2f(sb[1] * SCL) * invl;
                p[2] = exp2f(sb[2] * SCL) * invl;
                p[3] = exp2f(sb[3] * SCL) * invl;
                __builtin_nontemporal_store(
                    p, (f32x4*)(attn_base + kt * 64 + kp * 32 + lg * 8 + ch * 4));
                pa[ch * 4 + 0] = (bf16_t)p[0];
                pa[ch * 4 + 1] = (bf16_t)p[1];
                pa[ch * 4 + 2] = (bf16_t)p[2];
                pa[ch * 4 + 3] = (bf16_t)p[3];
            }
#pragma unroll
            for (int nd = 0; nd < 4; ++nd) {
                const int vr = nd * 16 + lr;
                const int hv = (vr & 3) | (((vr >> 3) & 1) << 2);
                bf16x8 vb = *(const bf16x8*)&Vs[buf][vr * 64 + (((kp * 4 + lg) ^ hv)) * 8];
                cacc[nd] = __builtin_amdgcn_mfma_f32_16x16x32_bf16(pa, vb, cacc[nd], 0, 0, 0);
            }
            __builtin_amdgcn_s_setprio(0);
        }
        if (kt + 2 < 32) {
            const int nb = (kt + 2) % 3;
            STAGE_K(kt + 2, nb);
            STAGE_V(kt + 2, nb);
        }
    }
#pragma unroll
    for (int nd = 0; nd < 4; ++nd)
#pragma unroll
        for (int r = 0; r < 4; ++r)
            ctx[((size_t)b * Ss + q0 + lg * 4 + r) * 1024 + h * 64 + nd * 16 + lr] =
                (bf16_t)cacc[nd][r];
#undef STAGE_K
#undef STAGE_V
}

// =====================  launcher  =====================
extern "C" void kernel_launch(void* const* d_in, const int* in_sizes, int n_in,
                              void* d_out, int out_size, void* d_ws, size_t ws_size,
                              hipStream_t stream) {
    const float* inp  = (const float*)d_in[0];
    const float* wq   = (const float*)d_in[1];
    const float* bq   = (const float*)d_in[2];
    const float* wk   = (const float*)d_in[3];
    const float* bk   = (const float*)d_in[4];
    const float* wv   = (const float*)d_in[5];
    const float* bv   = (const float*)d_in[6];
    const float* wo   = (const float*)d_in[7];
    const float* bo   = (const float*)d_in[8];
    const float* ln1g = (const float*)d_in[9];
    const float* ln1b = (const float*)d_in[10];
    const float* wi0  = (const float*)d_in[11];
    const float* bi0  = (const float*)d_in[12];
    const float* wi1  = (const float*)d_in[13];
    const float* bi1  = (const float*)d_in[14];
    const float* wff  = (const float*)d_in[15];
    const float* bff  = (const float*)d_in[16];
    const float* ln2g = (const float*)d_in[17];
    const float* ln2b = (const float*)d_in[18];

    // ---- workspace layout (152 MiB envelope, time-disjoint reuse) ----
    const size_t M1 = 1u << 20;
    bf16_t* wsb  = (bf16_t*)d_ws;
    bf16_t* wqT  = wsb + 0 * M1;
    bf16_t* wkT  = wsb + 1 * M1;
    bf16_t* wvT  = wsb + 2 * M1;
    bf16_t* woT  = wsb + 3 * M1;
    bf16_t* wi0T = wsb + 4 * M1;
    bf16_t* wi1T = wsb + 8 * M1;
    bf16_t* wffT = wsb + 12 * M1;
    bf16_t* hbuf = wsb + 16 * M1;            // LN out; dead after geglu
    bf16_t* qbuf = wsb + 20 * M1;
    bf16_t* kbuf = wsb + 24 * M1;
    bf16_t* vTb  = wsb + 28 * M1;            // [B,H,DK,S]
    bf16_t* ctxb = wsb + 32 * M1;            // dead after WO
    float*  h1   = (float*)(wsb + 36 * M1);  // 4M f32 (36M..44M slots)
    bf16_t* gbuf = wsb + 44 * M1;            // geglu out (44M..60M)
    float*  part = (float*)(wsb + 20 * M1);  // splitK partials (20M..36M slots; qbuf dead)
    float*  cb   = (float*)(wsb + 60 * M1);  // qkv bias concat (consumed step 3)

    float* out  = (float*)d_out;
    float* attn = out + (size_t)TOK * Dd;

    // 1) all weights transposed->bf16 + qkv bias concat, one launch
    transpose_all<<<16385, 256, 0, stream>>>(wq, wk, wv, wo, wi0, wi1, wff,
                                             wqT, wkT, wvT, woT, wi0T, wi1T, wffT,
                                             bq, bk, bv, cb);

    // 2) LN1
    ln_fwd<<<TOK, 256, 0, stream>>>(inp, ln1g, ln1b, hbuf);

    // 3) fused QKV projection, 128x128 (768 blocks = 3/CU)
    gemm_t<128, 128, 3><<<dim3(24, 32), 256, 0, stream>>>(
        hbuf, wqT, cb, nullptr, qbuf, kbuf, vTb, TOK, 3072, 1024, 1024);

    // 4) fused attention (512 blocks x 8 waves)
    attn_fused<<<Bb * Hh * (Ss / 128), 512, 0, stream>>>(qbuf, kbuf, vTb, attn, ctxb);

    // 5) output projection + residual -> h1 (f32), 64x64 (1024 blocks)
    gemm_t<64, 64, 1><<<dim3(16, 64), 256, 0, stream>>>(
        ctxb, woT, bo, inp, h1, nullptr, nullptr, TOK, 1024, 1024, 1024);

    // 6) LN2
    ln_fwd<<<TOK, 256, 0, stream>>>(h1, ln2g, ln2b, hbuf);

    // 7) fused FFN-up + GeGLU -> gbuf (2048 blocks)
    gemm_geglu<<<dim3(64, 32), 256, 0, stream>>>(hbuf, wi0T, wi1T, bi0, bi1, gbuf);

    // 8) down projection 128x64, split-K=2 -> partials (1024 blocks = 4/CU)
    gemm_t<128, 64, 4><<<dim3(16, 32, 2), 256, 0, stream>>>(
        gbuf, wffT, bff, nullptr, part, nullptr, nullptr, TOK, 1024, 2048, 4096);

    // 9) reduce partials + bias + residual -> out
    reduce2<<<4096, 256, 0, stream>>>(part, h1, bff, out);
}

// Round 12
// 475.123 us; speedup vs baseline: 1.2096x; 1.2096x over previous
//
#include <hip/hip_runtime.h>
#include <hip/hip_bf16.h>
#include <cstdint>

#define DEV __device__ __forceinline__

typedef __bf16 bf16_t;
typedef __bf16 bf16x8 __attribute__((ext_vector_type(8)));
typedef __bf16 bf16x4 __attribute__((ext_vector_type(4)));
typedef float  f32x4  __attribute__((ext_vector_type(4)));

constexpr int Bb = 2, Ss = 2048, Dd = 1024, Hh = 16, DKk = 64, FFf = 4096;
constexpr int TOK = Bb * Ss;          // 4096 tokens
constexpr float LN_EPS = 1e-6f;

// ---- async global->LDS, 16B per lane (wave-uniform base + lane*16) ----
DEV void g2l16(const void* g, void* l) {
    __builtin_amdgcn_global_load_lds(
        (const __attribute__((address_space(1))) unsigned int*)g,
        (__attribute__((address_space(3))) unsigned int*)l, 16, 0, 0);
}

#define WAITCNT(N) asm volatile("s_waitcnt vmcnt(" #N ")" ::: "memory")
#define SCHEDB() __builtin_amdgcn_sched_barrier(0)

// ==========  ALL weights fp32 [K,N] -> bf16 [N,K] + bias concat, one launch =
__global__ __launch_bounds__(256)
void transpose_all(const float* __restrict__ wq, const float* __restrict__ wk,
                   const float* __restrict__ wv, const float* __restrict__ wo,
                   const float* __restrict__ wi0, const float* __restrict__ wi1,
                   const float* __restrict__ wff,
                   bf16_t* wqT, bf16_t* wkT, bf16_t* wvT, bf16_t* woT,
                   bf16_t* wi0T, bf16_t* wi1T, bf16_t* wffT,
                   const float* __restrict__ bq, const float* __restrict__ bk,
                   const float* __restrict__ bv, float* __restrict__ cb) {
    __shared__ float t[32][33];
    const int id = blockIdx.x;
    if (id == 16384) {      // bias concat block
        const int tid = threadIdx.x;
#pragma unroll
        for (int i = 0; i < 4; ++i) {
            const int j = i * 256 + tid;
            cb[j] = bq[j]; cb[1024 + j] = bk[j]; cb[2048 + j] = bv[j];
        }
        return;
    }
    const float* src; bf16_t* dst; int K, N, tt;
    if (id < 4096) {
        const int w = id >> 10; tt = id & 1023; K = 1024; N = 1024;
        src = w == 0 ? wq : w == 1 ? wk : w == 2 ? wv : wo;
        dst = w == 0 ? wqT : w == 1 ? wkT : w == 2 ? wvT : woT;
    } else if (id < 12288) {
        const int w = (id - 4096) >> 12; tt = (id - 4096) & 4095; K = 1024; N = 4096;
        src = w ? wi1 : wi0; dst = w ? wi1T : wi0T;
    } else {
        tt = id - 12288; K = 4096; N = 1024;
        src = wff; dst = wffT;
    }
    const int ntn = N >> 5;
    const int n0 = (tt % ntn) * 32, k0 = (tt / ntn) * 32;
    const int tx = threadIdx.x & 31, ty = threadIdx.x >> 5;
#pragma unroll
    for (int i = 0; i < 4; ++i)
        t[ty + 8 * i][tx] = src[(size_t)(k0 + ty + 8 * i) * N + n0 + tx];
    __syncthreads();
#pragma unroll
    for (int i = 0; i < 4; ++i)
        dst[(size_t)(n0 + ty + 8 * i) * K + k0 + tx] = (bf16_t)t[tx][ty + 8 * i];
}

// =====================  LayerNorm fp32 -> bf16  =====================
__global__ __launch_bounds__(256)
void ln_fwd(const float* __restrict__ x, const float* __restrict__ g,
            const float* __restrict__ b, bf16_t* __restrict__ out) {
    __shared__ float red[8];
    const int row = blockIdx.x, tid = threadIdx.x;
    const float4 v = ((const float4*)(x + (size_t)row * Dd))[tid];
    float s  = v.x + v.y + v.z + v.w;
    float sq = v.x * v.x + v.y * v.y + v.z * v.z + v.w * v.w;
#pragma unroll
    for (int o = 32; o; o >>= 1) { s += __shfl_xor(s, o); sq += __shfl_xor(sq, o); }
    if ((tid & 63) == 0) { red[tid >> 6] = s; red[4 + (tid >> 6)] = sq; }
    __syncthreads();
    s  = red[0] + red[1] + red[2] + red[3];
    sq = red[4] + red[5] + red[6] + red[7];
    const float mean = s * (1.f / Dd);
    const float var  = sq * (1.f / Dd) - mean * mean;
    const float rs   = rsqrtf(var + LN_EPS);
    const float4 gv = ((const float4*)g)[tid];
    const float4 bv = ((const float4*)b)[tid];
    bf16x4 o4;
    o4[0] = (bf16_t)((v.x - mean) * rs * gv.x + bv.x);
    o4[1] = (bf16_t)((v.y - mean) * rs * gv.y + bv.y);
    o4[2] = (bf16_t)((v.z - mean) * rs * gv.z + bv.z);
    o4[3] = (bf16_t)((v.w - mean) * rs * gv.w + bv.w);
    ((bf16x4*)(out + (size_t)row * Dd))[tid] = o4;
}

// ---- shared GEMM epilogue ----
template <int EPI>
DEV void gemm_epi(float val, int gr, int gc, int N, size_t zofs,
                  void* outp, void* out2, void* out3, const float* resid) {
    if constexpr (EPI == 0) {
        ((bf16_t*)outp)[(size_t)gr * N + gc] = (bf16_t)val;
    } else if constexpr (EPI == 1) {
        const size_t idx = (size_t)gr * N + gc;
        ((float*)outp)[idx] = val + resid[idx];
    } else if constexpr (EPI == 4) {
        ((float*)outp)[zofs + (size_t)gr * N + gc] = val;   // split-K partial
    } else {
        const int sel = gc >> 10, col = gc & 1023;
        if (sel == 0) {
            ((bf16_t*)outp)[(size_t)gr * 1024 + col] = (bf16_t)val;
        } else if (sel == 1) {
            ((bf16_t*)out2)[(size_t)gr * 1024 + col] = (bf16_t)val;
        } else {
            const int bb = gr >> 11, sS = gr & 2047;
            ((bf16_t*)out3)[((size_t)bb << 21) + ((size_t)col << 11) + sS] = (bf16_t)val;
        }
    }
}

// =====================  GEMM: C = A[M,ld] @ Bt[N,ld]^T + bias  ==============
template <int BM, int BN, int EPI>
__global__ __launch_bounds__(256)
void gemm_t(const bf16_t* __restrict__ A, const bf16_t* __restrict__ Bt,
            const float* __restrict__ bias, const float* __restrict__ resid,
            void* __restrict__ outp, void* __restrict__ out2,
            void* __restrict__ out3, int M, int N, int K, int ld) {
    constexpr int WM = BM / 2, WN = BN / 2;
    constexpr int MI = WM / 16, NI = WN / 16;
    constexpr int CA = BM / 32, CB = BN / 32;
    __shared__ bf16_t As[BM * 64];
    __shared__ bf16_t Bs[BN * 64];
    const int tid = threadIdx.x;
    const int lane = tid & 63;
    const int wave = tid >> 6;
    const int wr = wave >> 1, wc = wave & 1;
    const int m0 = blockIdx.y * BM, n0 = blockIdx.x * BN;
    const int koff = blockIdx.z * K;
    const size_t zofs = (size_t)blockIdx.z * M * N;
    const int lr = lane & 15, lg = lane >> 4;

    const f32x4 z0 = {0.f, 0.f, 0.f, 0.f};
    f32x4 acc[MI][NI];
#pragma unroll
    for (int i = 0; i < MI; ++i)
#pragma unroll
        for (int j = 0; j < NI; ++j) acc[i][j] = z0;

    for (int k0 = 0; k0 < K; k0 += 64) {
#pragma unroll
        for (int c = 0; c < CA; ++c) {
            const int lin = c * 256 + tid;
            const int row = lin >> 3, col = (lin & 7) * 8;
            g2l16(A + (size_t)(m0 + row) * ld + koff + k0 + col, (char*)As + lin * 16);
        }
#pragma unroll
        for (int c = 0; c < CB; ++c) {
            const int lin = c * 256 + tid;
            const int row = lin >> 3, col = (lin & 7) * 8;
            g2l16(Bt + (size_t)(n0 + row) * ld + koff + k0 + col, (char*)Bs + lin * 16);
        }
        __syncthreads();

        bf16x8 af[2][MI], bw[2][NI];
#pragma unroll
        for (int kk = 0; kk < 2; ++kk)
#pragma unroll
            for (int mi = 0; mi < MI; ++mi)
                af[kk][mi] = *(const bf16x8*)(As + (wr * WM + mi * 16 + lr) * 64 +
                                              kk * 32 + lg * 8);
#pragma unroll
        for (int kk = 0; kk < 2; ++kk)
#pragma unroll
            for (int ni = 0; ni < NI; ++ni)
                bw[kk][ni] = *(const bf16x8*)(Bs + (wc * WN + ni * 16 + lr) * 64 +
                                              kk * 32 + lg * 8);
#pragma unroll
        for (int mi = 0; mi < MI; ++mi)
#pragma unroll
            for (int ni = 0; ni < NI; ++ni) {
                acc[mi][ni] = __builtin_amdgcn_mfma_f32_16x16x32_bf16(
                    af[0][mi], bw[0][ni], acc[mi][ni], 0, 0, 0);
                acc[mi][ni] = __builtin_amdgcn_mfma_f32_16x16x32_bf16(
                    af[1][mi], bw[1][ni], acc[mi][ni], 0, 0, 0);
            }
        __syncthreads();
    }

#pragma unroll
    for (int mi = 0; mi < MI; ++mi)
#pragma unroll
        for (int ni = 0; ni < NI; ++ni) {
            const int gc = n0 + wc * WN + ni * 16 + lr;
            const int gr0 = m0 + wr * WM + mi * 16 + lg * 4;
            const float bvl = (EPI == 4) ? 0.f : bias[gc];
#pragma unroll
            for (int r = 0; r < 4; ++r)
                gemm_epi<EPI>(acc[mi][ni][r] + bvl, gr0 + r, gc, N, zofs,
                              outp, out2, out3, resid);
        }
}

// =====================  split-K=2 reduce: out = p0+p1+bff+h1  ================
__global__ __launch_bounds__(256)
void reduce2(const float* __restrict__ part, const float* __restrict__ h1,
             const float* __restrict__ bff, float* __restrict__ out) {
    const int row = blockIdx.x, tid = threadIdx.x;
    const size_t idx = (size_t)row * 1024 + tid * 4;
    const float4 a = *(const float4*)(part + idx);
    const float4 b = *(const float4*)(part + (size_t)4096 * 1024 + idx);
    const float4 r = *(const float4*)(h1 + idx);
    const float4 bv = *(const float4*)(bff + tid * 4);
    float4 o;
    o.x = a.x + b.x + r.x + bv.x;
    o.y = a.y + b.y + r.y + bv.y;
    o.z = a.z + b.z + r.z + bv.z;
    o.w = a.w + b.w + r.w + bv.w;
    *(float4*)(out + idx) = o;
}

// =====================  fused FFN-up + GeGLU  ================================
__global__ __launch_bounds__(256)
void gemm_geglu(const bf16_t* __restrict__ A, const bf16_t* __restrict__ Bg,
                const bf16_t* __restrict__ Bl, const float* __restrict__ bi0,
                const float* __restrict__ bi1, bf16_t* __restrict__ gout) {
    __shared__ bf16_t As[128 * 64];
    __shared__ bf16_t Bgs[64 * 64];
    __shared__ bf16_t Bls[64 * 64];
    const int tid = threadIdx.x;
    const int lane = tid & 63;
    const int wave = tid >> 6;
    const int wr = wave >> 1, wc = wave & 1;
    const int m0 = blockIdx.y * 128, n0 = blockIdx.x * 64;
    const int lr = lane & 15, lg = lane >> 4;

    const f32x4 z0 = {0.f, 0.f, 0.f, 0.f};
    f32x4 ag[4][2], al[4][2];
#pragma unroll
    for (int i = 0; i < 4; ++i)
#pragma unroll
        for (int j = 0; j < 2; ++j) { ag[i][j] = z0; al[i][j] = z0; }

    for (int k0 = 0; k0 < 1024; k0 += 64) {
#pragma unroll
        for (int c = 0; c < 4; ++c) {
            const int lin = c * 256 + tid;
            const int row = lin >> 3, col = (lin & 7) * 8;
            g2l16(A + (size_t)(m0 + row) * 1024 + k0 + col, (char*)As + lin * 16);
        }
#pragma unroll
        for (int c = 0; c < 2; ++c) {
            const int lin = c * 256 + tid;
            const int row = lin >> 3, col = (lin & 7) * 8;
            g2l16(Bg + (size_t)(n0 + row) * 1024 + k0 + col, (char*)Bgs + lin * 16);
        }
#pragma unroll
        for (int c = 0; c < 2; ++c) {
            const int lin = c * 256 + tid;
            const int row = lin >> 3, col = (lin & 7) * 8;
            g2l16(Bl + (size_t)(n0 + row) * 1024 + k0 + col, (char*)Bls + lin * 16);
        }
        __syncthreads();

        bf16x8 af[2][4], bg[2][2], bl[2][2];
#pragma unroll
        for (int kk = 0; kk < 2; ++kk) {
#pragma unroll
            for (int mi = 0; mi < 4; ++mi)
                af[kk][mi] = *(const bf16x8*)(As + (wr * 64 + mi * 16 + lr) * 64 +
                                              kk * 32 + lg * 8);
#pragma unroll
            for (int ni = 0; ni < 2; ++ni) {
                bg[kk][ni] = *(const bf16x8*)(Bgs + (wc * 32 + ni * 16 + lr) * 64 +
                                              kk * 32 + lg * 8);
                bl[kk][ni] = *(const bf16x8*)(Bls + (wc * 32 + ni * 16 + lr) * 64 +
                                              kk * 32 + lg * 8);
            }
        }
#pragma unroll
        for (int mi = 0; mi < 4; ++mi)
#pragma unroll
            for (int ni = 0; ni < 2; ++ni) {
#pragma unroll
                for (int kk = 0; kk < 2; ++kk) {
                    ag[mi][ni] = __builtin_amdgcn_mfma_f32_16x16x32_bf16(
                        af[kk][mi], bg[kk][ni], ag[mi][ni], 0, 0, 0);
                    al[mi][ni] = __builtin_amdgcn_mfma_f32_16x16x32_bf16(
                        af[kk][mi], bl[kk][ni], al[mi][ni], 0, 0, 0);
                }
            }
        __syncthreads();
    }

#pragma unroll
    for (int mi = 0; mi < 4; ++mi)
#pragma unroll
        for (int ni = 0; ni < 2; ++ni) {
            const int gc = n0 + wc * 32 + ni * 16 + lr;
            const int gr0 = m0 + wr * 64 + mi * 16 + lg * 4;
            const float b0 = bi0[gc], b1 = bi1[gc];
#pragma unroll
            for (int r = 0; r < 4; ++r) {
                const float x = ag[mi][ni][r] + b0;
                const float y = al[mi][ni][r] + b1;
                const float ge = 0.5f * x * (1.f + erff(x * 0.70710678118654752f));
                gout[(size_t)(gr0 + r) * 4096 + gc] = (bf16_t)(ge * y);
            }
        }
}

// ===========  fused attention v7 (round-9 proven: inline regular stores) ====
__global__ __launch_bounds__(512)
void attn_fused(const bf16_t* __restrict__ q, const bf16_t* __restrict__ k,
                const bf16_t* __restrict__ vT, float* __restrict__ attn,
                bf16_t* __restrict__ ctx) {
    __shared__ bf16_t Ks[3][64 * 64];
    __shared__ bf16_t Vs[3][64 * 64];
    const int tid = threadIdx.x, lane = tid & 63, wave = tid >> 6;   // 8 waves
    const int lr = lane & 15, lg = lane >> 4;
    int blk = blockIdx.x;
    blk = (blk & 7) * 64 + (blk >> 3);       // XCD swizzle (512 % 8 == 0)
    const int qc = blk & 15, bh = blk >> 4;
    const int b = bh >> 4, h = bh & 15;
    const int q0 = qc * 128 + wave * 16;
    const size_t base = (size_t)b * (Ss * 1024) + h * 64;
    constexpr float SCL = 0.125f * 1.4426950408889634f;   // 1/sqrt(64) * log2(e)
    const f32x4 z0 = {0.f, 0.f, 0.f, 0.f};

    const int st_r8 = lane >> 3;
    const int st_row = wave * 8 + st_r8;
    const int st_c0 = (lane & 7) ^ (st_r8 & 3) ^ ((wave & 1) << 2);

    const bf16x8 aq0 = *(const bf16x8*)(q + base + (size_t)(q0 + lr) * 1024 + lg * 8);
    const bf16x8 aq1 = *(const bf16x8*)(q + base + (size_t)(q0 + lr) * 1024 + 32 + lg * 8);
    const bf16_t* kb = k + base;
    const bf16_t* vb_base = vT + ((size_t)bh * 64) * Ss;

#define STAGE_K(kt_, buf_)                                                       \
    g2l16(kb + (size_t)((kt_) * 64 + st_row) * 1024 + st_c0 * 8,                 \
          &Ks[buf_][wave * 512]);
#define STAGE_V(kt_, buf_)                                                       \
    g2l16(vb_base + (size_t)st_row * Ss + (kt_) * 64 + st_c0 * 8,                \
          &Vs[buf_][wave * 512]);

    // ---- pass A: esum ----
    f32x4 ea = z0, eb = z0;
    STAGE_K(0, 0);
    STAGE_K(1, 1);
    for (int kt = 0; kt < 32; ++kt) {
        const int buf = kt % 3;
        if (kt == 31) { WAITCNT(0); } else { WAITCNT(1); }
        SCHEDB();
        __builtin_amdgcn_s_barrier();
        SCHEDB();
        f32x4 sa[4];
        __builtin_amdgcn_s_setprio(1);
#pragma unroll
        for (int ct = 0; ct < 4; ++ct) {
            const int ar = ct * 16 + lr;
            const int hz = (ar & 3) | (((ar >> 3) & 1) << 2);
            bf16x8 k0 = *(const bf16x8*)&Ks[buf][ar * 64 + (lg ^ hz) * 8];
            bf16x8 k1 = *(const bf16x8*)&Ks[buf][ar * 64 + (((4 + lg) ^ hz)) * 8];
            sa[ct] = __builtin_amdgcn_mfma_f32_16x16x32_bf16(k0, aq0, z0, 0, 0, 0);
            sa[ct] = __builtin_amdgcn_mfma_f32_16x16x32_bf16(k1, aq1, sa[ct], 0, 0, 0);
        }
        __builtin_amdgcn_s_setprio(0);
#pragma unroll
        for (int r = 0; r < 4; ++r) {
            ea[r] += exp2f(sa[0][r] * SCL) + exp2f(sa[1][r] * SCL);
            eb[r] += exp2f(sa[2][r] * SCL) + exp2f(sa[3][r] * SCL);
        }
        if (kt + 2 < 32) STAGE_K(kt + 2, (kt + 2) % 3);
    }
    float e = ((ea[0] + ea[1]) + (ea[2] + ea[3])) + ((eb[0] + eb[1]) + (eb[2] + eb[3]));
    e += __shfl_xor(e, 16);
    e += __shfl_xor(e, 32);
    const float invl = 1.f / e;

    f32x4 cacc[4];
#pragma unroll
    for (int nd = 0; nd < 4; ++nd) cacc[nd] = z0;

    float* attn_base = attn + ((size_t)bh * Ss + q0 + lr) * Ss;

    __builtin_amdgcn_s_barrier();   // all waves done reading pass-A buffers
    SCHEDB();

    // ---- pass B ----
    STAGE_K(0, 0); STAGE_V(0, 0);
    STAGE_K(1, 1); STAGE_V(1, 1);
    for (int kt = 0; kt < 32; ++kt) {
        const int buf = kt % 3;
        if (kt == 0) { WAITCNT(2); }
        else if (kt == 31) { WAITCNT(4); }
        else { WAITCNT(6); }
        SCHEDB();
        __builtin_amdgcn_s_barrier();
        SCHEDB();
#pragma unroll
        for (int kp = 0; kp < 2; ++kp) {
            bf16x8 pa;
            __builtin_amdgcn_s_setprio(1);
#pragma unroll
            for (int ch = 0; ch < 2; ++ch) {
                const int pr = kp * 32 + (lr >> 2) * 8 + ch * 4 + (lr & 3);
                const int hz = (pr & 3) | (((pr >> 3) & 1) << 2);
                bf16x8 k0 = *(const bf16x8*)&Ks[buf][pr * 64 + (lg ^ hz) * 8];
                bf16x8 k1 = *(const bf16x8*)&Ks[buf][pr * 64 + (((4 + lg) ^ hz)) * 8];
                f32x4 sb = __builtin_amdgcn_mfma_f32_16x16x32_bf16(k0, aq0, z0, 0, 0, 0);
                sb = __builtin_amdgcn_mfma_f32_16x16x32_bf16(k1, aq1, sb, 0, 0, 0);
                float4 p;
                p.x = exp2f(sb[0] * SCL) * invl;
                p.y = exp2f(sb[1] * SCL) * invl;
                p.z = exp2f(sb[2] * SCL) * invl;
                p.w = exp2f(sb[3] * SCL) * invl;
                *(float4*)(attn_base + kt * 64 + kp * 32 + lg * 8 + ch * 4) = p;
                pa[ch * 4 + 0] = (bf16_t)p.x;
                pa[ch * 4 + 1] = (bf16_t)p.y;
                pa[ch * 4 + 2] = (bf16_t)p.z;
                pa[ch * 4 + 3] = (bf16_t)p.w;
            }
#pragma unroll
            for (int nd = 0; nd < 4; ++nd) {
                const int vr = nd * 16 + lr;
                const int hv = (vr & 3) | (((vr >> 3) & 1) << 2);
                bf16x8 vb = *(const bf16x8*)&Vs[buf][vr * 64 + (((kp * 4 + lg) ^ hv)) * 8];
                cacc[nd] = __builtin_amdgcn_mfma_f32_16x16x32_bf16(pa, vb, cacc[nd], 0, 0, 0);
            }
            __builtin_amdgcn_s_setprio(0);
        }
        if (kt + 2 < 32) {
            const int nb = (kt + 2) % 3;
            STAGE_K(kt + 2, nb);
            STAGE_V(kt + 2, nb);
        }
    }
#pragma unroll
    for (int nd = 0; nd < 4; ++nd)
#pragma unroll
        for (int r = 0; r < 4; ++r)
            ctx[((size_t)b * Ss + q0 + lg * 4 + r) * 1024 + h * 64 + nd * 16 + lr] =
                (bf16_t)cacc[nd][r];
#undef STAGE_K
#undef STAGE_V
}

// =====================  launcher  =====================
extern "C" void kernel_launch(void* const* d_in, const int* in_sizes, int n_in,
                              void* d_out, int out_size, void* d_ws, size_t ws_size,
                              hipStream_t stream) {
    const float* inp  = (const float*)d_in[0];
    const float* wq   = (const float*)d_in[1];
    const float* bq   = (const float*)d_in[2];
    const float* wk   = (const float*)d_in[3];
    const float* bk   = (const float*)d_in[4];
    const float* wv   = (const float*)d_in[5];
    const float* bv   = (const float*)d_in[6];
    const float* wo   = (const float*)d_in[7];
    const float* bo   = (const float*)d_in[8];
    const float* ln1g = (const float*)d_in[9];
    const float* ln1b = (const float*)d_in[10];
    const float* wi0  = (const float*)d_in[11];
    const float* bi0  = (const float*)d_in[12];
    const float* wi1  = (const float*)d_in[13];
    const float* bi1  = (const float*)d_in[14];
    const float* wff  = (const float*)d_in[15];
    const float* bff  = (const float*)d_in[16];
    const float* ln2g = (const float*)d_in[17];
    const float* ln2b = (const float*)d_in[18];

    // ---- workspace layout (152 MiB envelope, time-disjoint reuse) ----
    const size_t M1 = 1u << 20;
    bf16_t* wsb  = (bf16_t*)d_ws;
    bf16_t* wqT  = wsb + 0 * M1;
    bf16_t* wkT  = wsb + 1 * M1;
    bf16_t* wvT  = wsb + 2 * M1;
    bf16_t* woT  = wsb + 3 * M1;
    bf16_t* wi0T = wsb + 4 * M1;
    bf16_t* wi1T = wsb + 8 * M1;
    bf16_t* wffT = wsb + 12 * M1;
    bf16_t* hbuf = wsb + 16 * M1;            // LN out; dead after geglu
    bf16_t* qbuf = wsb + 20 * M1;
    bf16_t* kbuf = wsb + 24 * M1;
    bf16_t* vTb  = wsb + 28 * M1;            // [B,H,DK,S]
    bf16_t* ctxb = wsb + 32 * M1;            // dead after WO
    float*  h1   = (float*)(wsb + 36 * M1);  // 4M f32 (36M..44M slots)
    bf16_t* gbuf = wsb + 44 * M1;            // geglu out (44M..60M)
    float*  part = (float*)(wsb + 20 * M1);  // splitK partials (20M..36M; qkv/ctx dead)
    float*  cb   = (float*)(wsb + 60 * M1);  // qkv bias concat (consumed step 3)

    float* out  = (float*)d_out;
    float* attn = out + (size_t)TOK * Dd;

    // 1) all weights transposed->bf16 + qkv bias concat, one launch
    transpose_all<<<16385, 256, 0, stream>>>(wq, wk, wv, wo, wi0, wi1, wff,
                                             wqT, wkT, wvT, woT, wi0T, wi1T, wffT,
                                             bq, bk, bv, cb);

    // 2) LN1
    ln_fwd<<<TOK, 256, 0, stream>>>(inp, ln1g, ln1b, hbuf);

    // 3) fused QKV projection, 128x128 (768 blocks = 3/CU)
    gemm_t<128, 128, 3><<<dim3(24, 32), 256, 0, stream>>>(
        hbuf, wqT, cb, nullptr, qbuf, kbuf, vTb, TOK, 3072, 1024, 1024);

    // 4) fused attention (512 blocks x 8 waves)
    attn_fused<<<Bb * Hh * (Ss / 128), 512, 0, stream>>>(qbuf, kbuf, vTb, attn, ctxb);

    // 5) output projection + residual -> h1 (f32), 64x64 (1024 blocks)
    gemm_t<64, 64, 1><<<dim3(16, 64), 256, 0, stream>>>(
        ctxb, woT, bo, inp, h1, nullptr, nullptr, TOK, 1024, 1024, 1024);

    // 6) LN2
    ln_fwd<<<TOK, 256, 0, stream>>>(h1, ln2g, ln2b, hbuf);

    // 7) fused FFN-up + GeGLU -> gbuf (2048 blocks)
    gemm_geglu<<<dim3(64, 32), 256, 0, stream>>>(hbuf, wi0T, wi1T, bi0, bi1, gbuf);

    // 8) down projection 128x64, split-K=2 -> partials (1024 blocks = 4/CU)
    gemm_t<128, 64, 4><<<dim3(16, 32, 2), 256, 0, stream>>>(
        gbuf, wffT, bff, nullptr, part, nullptr, nullptr, TOK, 1024, 2048, 4096);

    // 9) reduce partials + bias + residual -> out
    reduce2<<<4096, 256, 0, stream>>>(part, h1, bff, out);
}

// Round 13
// 470.178 us; speedup vs baseline: 1.2223x; 1.0105x over previous
//
#include <hip/hip_runtime.h>
#include <hip/hip_bf16.h>
#include <cstdint>

#define DEV __device__ __forceinline__

typedef __bf16 bf16_t;
typedef __bf16 bf16x8 __attribute__((ext_vector_type(8)));
typedef __bf16 bf16x4 __attribute__((ext_vector_type(4)));
typedef float  f32x4  __attribute__((ext_vector_type(4)));

constexpr int Bb = 2, Ss = 2048, Dd = 1024, Hh = 16, DKk = 64, FFf = 4096;
constexpr int TOK = Bb * Ss;          // 4096 tokens
constexpr float LN_EPS = 1e-6f;

// ---- async global->LDS, 16B per lane (wave-uniform base + lane*16) ----
DEV void g2l16(const void* g, void* l) {
    __builtin_amdgcn_global_load_lds(
        (const __attribute__((address_space(1))) unsigned int*)g,
        (__attribute__((address_space(3))) unsigned int*)l, 16, 0, 0);
}

#define WAITCNT(N) asm volatile("s_waitcnt vmcnt(" #N ")" ::: "memory")
#define SCHEDB() __builtin_amdgcn_sched_barrier(0)

// ==========  ALL weights fp32 [K,N] -> bf16 [N,K] + bias concat, one launch =
__global__ __launch_bounds__(256)
void transpose_all(const float* __restrict__ wq, const float* __restrict__ wk,
                   const float* __restrict__ wv, const float* __restrict__ wo,
                   const float* __restrict__ wi0, const float* __restrict__ wi1,
                   const float* __restrict__ wff,
                   bf16_t* wqT, bf16_t* wkT, bf16_t* wvT, bf16_t* woT,
                   bf16_t* wi0T, bf16_t* wi1T, bf16_t* wffT,
                   const float* __restrict__ bq, const float* __restrict__ bk,
                   const float* __restrict__ bv, float* __restrict__ cb) {
    __shared__ float t[32][33];
    const int id = blockIdx.x;
    if (id == 16384) {      // bias concat block
        const int tid = threadIdx.x;
#pragma unroll
        for (int i = 0; i < 4; ++i) {
            const int j = i * 256 + tid;
            cb[j] = bq[j]; cb[1024 + j] = bk[j]; cb[2048 + j] = bv[j];
        }
        return;
    }
    const float* src; bf16_t* dst; int K, N, tt;
    if (id < 4096) {
        const int w = id >> 10; tt = id & 1023; K = 1024; N = 1024;
        src = w == 0 ? wq : w == 1 ? wk : w == 2 ? wv : wo;
        dst = w == 0 ? wqT : w == 1 ? wkT : w == 2 ? wvT : woT;
    } else if (id < 12288) {
        const int w = (id - 4096) >> 12; tt = (id - 4096) & 4095; K = 1024; N = 4096;
        src = w ? wi1 : wi0; dst = w ? wi1T : wi0T;
    } else {
        tt = id - 12288; K = 4096; N = 1024;
        src = wff; dst = wffT;
    }
    const int ntn = N >> 5;
    const int n0 = (tt % ntn) * 32, k0 = (tt / ntn) * 32;
    const int tx = threadIdx.x & 31, ty = threadIdx.x >> 5;
#pragma unroll
    for (int i = 0; i < 4; ++i)
        t[ty + 8 * i][tx] = src[(size_t)(k0 + ty + 8 * i) * N + n0 + tx];
    __syncthreads();
#pragma unroll
    for (int i = 0; i < 4; ++i)
        dst[(size_t)(n0 + ty + 8 * i) * K + k0 + tx] = (bf16_t)t[tx][ty + 8 * i];
}

// =====================  LayerNorm fp32 -> bf16  =====================
__global__ __launch_bounds__(256)
void ln_fwd(const float* __restrict__ x, const float* __restrict__ g,
            const float* __restrict__ b, bf16_t* __restrict__ out) {
    __shared__ float red[8];
    const int row = blockIdx.x, tid = threadIdx.x;
    const float4 v = ((const float4*)(x + (size_t)row * Dd))[tid];
    float s  = v.x + v.y + v.z + v.w;
    float sq = v.x * v.x + v.y * v.y + v.z * v.z + v.w * v.w;
#pragma unroll
    for (int o = 32; o; o >>= 1) { s += __shfl_xor(s, o); sq += __shfl_xor(sq, o); }
    if ((tid & 63) == 0) { red[tid >> 6] = s; red[4 + (tid >> 6)] = sq; }
    __syncthreads();
    s  = red[0] + red[1] + red[2] + red[3];
    sq = red[4] + red[5] + red[6] + red[7];
    const float mean = s * (1.f / Dd);
    const float var  = sq * (1.f / Dd) - mean * mean;
    const float rs   = rsqrtf(var + LN_EPS);
    const float4 gv = ((const float4*)g)[tid];
    const float4 bv = ((const float4*)b)[tid];
    bf16x4 o4;
    o4[0] = (bf16_t)((v.x - mean) * rs * gv.x + bv.x);
    o4[1] = (bf16_t)((v.y - mean) * rs * gv.y + bv.y);
    o4[2] = (bf16_t)((v.z - mean) * rs * gv.z + bv.z);
    o4[3] = (bf16_t)((v.w - mean) * rs * gv.w + bv.w);
    ((bf16x4*)(out + (size_t)row * Dd))[tid] = o4;
}

// ---- shared GEMM epilogue ----
template <int EPI>
DEV void gemm_epi(float val, int gr, int gc, int N, size_t zofs,
                  void* outp, void* out2, void* out3, const float* resid) {
    if constexpr (EPI == 0) {
        ((bf16_t*)outp)[(size_t)gr * N + gc] = (bf16_t)val;
    } else if constexpr (EPI == 1) {
        const size_t idx = (size_t)gr * N + gc;
        ((float*)outp)[idx] = val + resid[idx];
    } else if constexpr (EPI == 4) {
        ((float*)outp)[zofs + (size_t)gr * N + gc] = val;   // split-K partial
    } else {
        const int sel = gc >> 10, col = gc & 1023;
        if (sel == 0) {
            ((bf16_t*)outp)[(size_t)gr * 1024 + col] = (bf16_t)val;
        } else if (sel == 1) {
            ((bf16_t*)out2)[(size_t)gr * 1024 + col] = (bf16_t)val;
        } else {
            const int bb = gr >> 11, sS = gr & 2047;
            ((bf16_t*)out3)[((size_t)bb << 21) + ((size_t)col << 11) + sS] = (bf16_t)val;
        }
    }
}

// =====================  GEMM: C = A[M,ld] @ Bt[N,ld]^T + bias  ==============
template <int BM, int BN, int EPI>
__global__ __launch_bounds__(256)
void gemm_t(const bf16_t* __restrict__ A, const bf16_t* __restrict__ Bt,
            const float* __restrict__ bias, const float* __restrict__ resid,
            void* __restrict__ outp, void* __restrict__ out2,
            void* __restrict__ out3, int M, int N, int K, int ld) {
    constexpr int WM = BM / 2, WN = BN / 2;
    constexpr int MI = WM / 16, NI = WN / 16;
    constexpr int CA = BM / 32, CB = BN / 32;
    __shared__ bf16_t As[BM * 64];
    __shared__ bf16_t Bs[BN * 64];
    const int tid = threadIdx.x;
    const int lane = tid & 63;
    const int wave = tid >> 6;
    const int wr = wave >> 1, wc = wave & 1;
    const int m0 = blockIdx.y * BM, n0 = blockIdx.x * BN;
    const int koff = blockIdx.z * K;
    const size_t zofs = (size_t)blockIdx.z * M * N;
    const int lr = lane & 15, lg = lane >> 4;

    const f32x4 z0 = {0.f, 0.f, 0.f, 0.f};
    f32x4 acc[MI][NI];
#pragma unroll
    for (int i = 0; i < MI; ++i)
#pragma unroll
        for (int j = 0; j < NI; ++j) acc[i][j] = z0;

    for (int k0 = 0; k0 < K; k0 += 64) {
#pragma unroll
        for (int c = 0; c < CA; ++c) {
            const int lin = c * 256 + tid;
            const int row = lin >> 3, col = (lin & 7) * 8;
            g2l16(A + (size_t)(m0 + row) * ld + koff + k0 + col, (char*)As + lin * 16);
        }
#pragma unroll
        for (int c = 0; c < CB; ++c) {
            const int lin = c * 256 + tid;
            const int row = lin >> 3, col = (lin & 7) * 8;
            g2l16(Bt + (size_t)(n0 + row) * ld + koff + k0 + col, (char*)Bs + lin * 16);
        }
        __syncthreads();

        bf16x8 af[2][MI], bw[2][NI];
#pragma unroll
        for (int kk = 0; kk < 2; ++kk)
#pragma unroll
            for (int mi = 0; mi < MI; ++mi)
                af[kk][mi] = *(const bf16x8*)(As + (wr * WM + mi * 16 + lr) * 64 +
                                              kk * 32 + lg * 8);
#pragma unroll
        for (int kk = 0; kk < 2; ++kk)
#pragma unroll
            for (int ni = 0; ni < NI; ++ni)
                bw[kk][ni] = *(const bf16x8*)(Bs + (wc * WN + ni * 16 + lr) * 64 +
                                              kk * 32 + lg * 8);
#pragma unroll
        for (int mi = 0; mi < MI; ++mi)
#pragma unroll
            for (int ni = 0; ni < NI; ++ni) {
                acc[mi][ni] = __builtin_amdgcn_mfma_f32_16x16x32_bf16(
                    af[0][mi], bw[0][ni], acc[mi][ni], 0, 0, 0);
                acc[mi][ni] = __builtin_amdgcn_mfma_f32_16x16x32_bf16(
                    af[1][mi], bw[1][ni], acc[mi][ni], 0, 0, 0);
            }
        __syncthreads();
    }

#pragma unroll
    for (int mi = 0; mi < MI; ++mi)
#pragma unroll
        for (int ni = 0; ni < NI; ++ni) {
            const int gc = n0 + wc * WN + ni * 16 + lr;
            const int gr0 = m0 + wr * WM + mi * 16 + lg * 4;
            const float bvl = (EPI == 4) ? 0.f : bias[gc];
#pragma unroll
            for (int r = 0; r < 4; ++r)
                gemm_epi<EPI>(acc[mi][ni][r] + bvl, gr0 + r, gc, N, zofs,
                              outp, out2, out3, resid);
        }
}

// =====================  split-K=2 reduce: out = p0+p1+bff+h1  ================
__global__ __launch_bounds__(256)
void reduce2(const float* __restrict__ part, const float* __restrict__ h1,
             const float* __restrict__ bff, float* __restrict__ out) {
    const int row = blockIdx.x, tid = threadIdx.x;
    const size_t idx = (size_t)row * 1024 + tid * 4;
    const float4 a = *(const float4*)(part + idx);
    const float4 b = *(const float4*)(part + (size_t)4096 * 1024 + idx);
    const float4 r = *(const float4*)(h1 + idx);
    const float4 bv = *(const float4*)(bff + tid * 4);
    float4 o;
    o.x = a.x + b.x + r.x + bv.x;
    o.y = a.y + b.y + r.y + bv.y;
    o.z = a.z + b.z + r.z + bv.z;
    o.w = a.w + b.w + r.w + bv.w;
    *(float4*)(out + idx) = o;
}

// =====================  fused FFN-up + GeGLU  ================================
__global__ __launch_bounds__(256)
void gemm_geglu(const bf16_t* __restrict__ A, const bf16_t* __restrict__ Bg,
                const bf16_t* __restrict__ Bl, const float* __restrict__ bi0,
                const float* __restrict__ bi1, bf16_t* __restrict__ gout) {
    __shared__ bf16_t As[128 * 64];
    __shared__ bf16_t Bgs[64 * 64];
    __shared__ bf16_t Bls[64 * 64];
    const int tid = threadIdx.x;
    const int lane = tid & 63;
    const int wave = tid >> 6;
    const int wr = wave >> 1, wc = wave & 1;
    const int m0 = blockIdx.y * 128, n0 = blockIdx.x * 64;
    const int lr = lane & 15, lg = lane >> 4;

    const f32x4 z0 = {0.f, 0.f, 0.f, 0.f};
    f32x4 ag[4][2], al[4][2];
#pragma unroll
    for (int i = 0; i < 4; ++i)
#pragma unroll
        for (int j = 0; j < 2; ++j) { ag[i][j] = z0; al[i][j] = z0; }

    for (int k0 = 0; k0 < 1024; k0 += 64) {
#pragma unroll
        for (int c = 0; c < 4; ++c) {
            const int lin = c * 256 + tid;
            const int row = lin >> 3, col = (lin & 7) * 8;
            g2l16(A + (size_t)(m0 + row) * 1024 + k0 + col, (char*)As + lin * 16);
        }
#pragma unroll
        for (int c = 0; c < 2; ++c) {
            const int lin = c * 256 + tid;
            const int row = lin >> 3, col = (lin & 7) * 8;
            g2l16(Bg + (size_t)(n0 + row) * 1024 + k0 + col, (char*)Bgs + lin * 16);
        }
#pragma unroll
        for (int c = 0; c < 2; ++c) {
            const int lin = c * 256 + tid;
            const int row = lin >> 3, col = (lin & 7) * 8;
            g2l16(Bl + (size_t)(n0 + row) * 1024 + k0 + col, (char*)Bls + lin * 16);
        }
        __syncthreads();

        bf16x8 af[2][4], bg[2][2], bl[2][2];
#pragma unroll
        for (int kk = 0; kk < 2; ++kk) {
#pragma unroll
            for (int mi = 0; mi < 4; ++mi)
                af[kk][mi] = *(const bf16x8*)(As + (wr * 64 + mi * 16 + lr) * 64 +
                                              kk * 32 + lg * 8);
#pragma unroll
            for (int ni = 0; ni < 2; ++ni) {
                bg[kk][ni] = *(const bf16x8*)(Bgs + (wc * 32 + ni * 16 + lr) * 64 +
                                              kk * 32 + lg * 8);
                bl[kk][ni] = *(const bf16x8*)(Bls + (wc * 32 + ni * 16 + lr) * 64 +
                                              kk * 32 + lg * 8);
            }
        }
#pragma unroll
        for (int mi = 0; mi < 4; ++mi)
#pragma unroll
            for (int ni = 0; ni < 2; ++ni) {
#pragma unroll
                for (int kk = 0; kk < 2; ++kk) {
                    ag[mi][ni] = __builtin_amdgcn_mfma_f32_16x16x32_bf16(
                        af[kk][mi], bg[kk][ni], ag[mi][ni], 0, 0, 0);
                    al[mi][ni] = __builtin_amdgcn_mfma_f32_16x16x32_bf16(
                        af[kk][mi], bl[kk][ni], al[mi][ni], 0, 0, 0);
                }
            }
        __syncthreads();
    }

#pragma unroll
    for (int mi = 0; mi < 4; ++mi)
#pragma unroll
        for (int ni = 0; ni < 2; ++ni) {
            const int gc = n0 + wc * 32 + ni * 16 + lr;
            const int gr0 = m0 + wr * 64 + mi * 16 + lg * 4;
            const float b0 = bi0[gc], b1 = bi1[gc];
#pragma unroll
            for (int r = 0; r < 4; ++r) {
                const float x = ag[mi][ni][r] + b0;
                const float y = al[mi][ni][r] + b1;
                const float ge = 0.5f * x * (1.f + erff(x * 0.70710678118654752f));
                gout[(size_t)(gr0 + r) * 4096 + gc] = (bf16_t)(ge * y);
            }
        }
}

// ======  fused attention v8: pass A KVBLK=128 (half the barriers), pass B ====
// unchanged from the proven round-9 schedule. Flat 48KB LDS:
//   pass A: 3 x 16KB K-buffers (128 rows x 64) at lds + i*8192
//   pass B: Ks[j] = lds + j*4096, Vs[j] = lds + (3+j)*4096 (time-disjoint)
__global__ __launch_bounds__(512)
void attn_fused(const bf16_t* __restrict__ q, const bf16_t* __restrict__ k,
                const bf16_t* __restrict__ vT, float* __restrict__ attn,
                bf16_t* __restrict__ ctx) {
    __shared__ bf16_t lds[6 * 4096];
    const int tid = threadIdx.x, lane = tid & 63, wave = tid >> 6;   // 8 waves
    const int lr = lane & 15, lg = lane >> 4;
    int blk = blockIdx.x;
    blk = (blk & 7) * 64 + (blk >> 3);       // XCD swizzle (512 % 8 == 0)
    const int qc = blk & 15, bh = blk >> 4;
    const int b = bh >> 4, h = bh & 15;
    const int q0 = qc * 128 + wave * 16;
    const size_t base = (size_t)b * (Ss * 1024) + h * 64;
    constexpr float SCL = 0.125f * 1.4426950408889634f;   // 1/sqrt(64) * log2(e)
    const f32x4 z0 = {0.f, 0.f, 0.f, 0.f};

    const int st_r8 = lane >> 3;
    // pass B (64-row tiles): row = wave*8 + st_r8 -> hz = (r8&3)|((wave&1)<<2)
    const int st_c0 = (lane & 7) ^ (st_r8 & 3) ^ ((wave & 1) << 2);
    // pass A (128-row tiles): row = wave*16 + i*8 + st_r8 -> hz = (r8&3)|((i&1)<<2)
    const int st_c0A = (lane & 7) ^ (st_r8 & 3);

    const bf16x8 aq0 = *(const bf16x8*)(q + base + (size_t)(q0 + lr) * 1024 + lg * 8);
    const bf16x8 aq1 = *(const bf16x8*)(q + base + (size_t)(q0 + lr) * 1024 + 32 + lg * 8);
    const bf16_t* kb = k + base;
    const bf16_t* vb_base = vT + ((size_t)bh * 64) * Ss;

// pass A staging: 128-row tile kt_, wave stages rows wave*16 + {0..7, 8..15}
#define STAGE_KA(kt_, buf_)                                                       \
    {                                                                             \
        g2l16(kb + (size_t)((kt_) * 128 + wave * 16 + st_r8) * 1024 + st_c0A * 8, \
              lds + (buf_) * 8192 + wave * 1024);                                 \
        g2l16(kb + (size_t)((kt_) * 128 + wave * 16 + 8 + st_r8) * 1024 +         \
                  (st_c0A ^ 4) * 8,                                               \
              lds + (buf_) * 8192 + wave * 1024 + 512);                           \
    }
// pass B staging (64-row tiles, as round 9)
#define STAGE_K(kt_, buf_)                                                        \
    g2l16(kb + (size_t)((kt_) * 64 + wave * 8 + st_r8) * 1024 + st_c0 * 8,        \
          lds + (buf_) * 4096 + wave * 512);
#define STAGE_V(kt_, buf_)                                                        \
    g2l16(vb_base + (size_t)(wave * 8 + st_r8) * Ss + (kt_) * 64 + st_c0 * 8,     \
          lds + (3 + (buf_)) * 4096 + wave * 512);

    // ---- pass A: esum over 16 tiles of 128 k-rows ----
    f32x4 ea = z0, eb = z0;
    STAGE_KA(0, 0);
    STAGE_KA(1, 1);
    for (int kt = 0; kt < 16; ++kt) {
        const int buf = kt % 3;
        if (kt == 15) { WAITCNT(0); } else { WAITCNT(2); }
        SCHEDB();
        __builtin_amdgcn_s_barrier();
        SCHEDB();
        f32x4 sa[8];
        __builtin_amdgcn_s_setprio(1);
#pragma unroll
        for (int ct = 0; ct < 8; ++ct) {
            const int ar = ct * 16 + lr;
            const int hz = (ar & 3) | (((ar >> 3) & 1) << 2);
            bf16x8 k0 = *(const bf16x8*)&lds[buf * 8192 + ar * 64 + (lg ^ hz) * 8];
            bf16x8 k1 = *(const bf16x8*)&lds[buf * 8192 + ar * 64 + (((4 + lg) ^ hz)) * 8];
            sa[ct] = __builtin_amdgcn_mfma_f32_16x16x32_bf16(k0, aq0, z0, 0, 0, 0);
            sa[ct] = __builtin_amdgcn_mfma_f32_16x16x32_bf16(k1, aq1, sa[ct], 0, 0, 0);
        }
        __builtin_amdgcn_s_setprio(0);
#pragma unroll
        for (int r = 0; r < 4; ++r) {
            ea[r] += exp2f(sa[0][r] * SCL) + exp2f(sa[1][r] * SCL) +
                     exp2f(sa[2][r] * SCL) + exp2f(sa[3][r] * SCL);
            eb[r] += exp2f(sa[4][r] * SCL) + exp2f(sa[5][r] * SCL) +
                     exp2f(sa[6][r] * SCL) + exp2f(sa[7][r] * SCL);
        }
        if (kt + 2 < 16) STAGE_KA(kt + 2, (kt + 2) % 3);
    }
    float e = ((ea[0] + ea[1]) + (ea[2] + ea[3])) + ((eb[0] + eb[1]) + (eb[2] + eb[3]));
    e += __shfl_xor(e, 16);
    e += __shfl_xor(e, 32);
    const float invl = 1.f / e;

    f32x4 cacc[4];
#pragma unroll
    for (int nd = 0; nd < 4; ++nd) cacc[nd] = z0;

    float* attn_base = attn + ((size_t)bh * Ss + q0 + lr) * Ss;

    __builtin_amdgcn_s_barrier();   // all waves done reading pass-A buffers
    SCHEDB();

    // ---- pass B (round-9 proven schedule) ----
    STAGE_K(0, 0); STAGE_V(0, 0);
    STAGE_K(1, 1); STAGE_V(1, 1);
    for (int kt = 0; kt < 32; ++kt) {
        const int buf = kt % 3;
        if (kt == 0) { WAITCNT(2); }
        else if (kt == 31) { WAITCNT(4); }
        else { WAITCNT(6); }
        SCHEDB();
        __builtin_amdgcn_s_barrier();
        SCHEDB();
#pragma unroll
        for (int kp = 0; kp < 2; ++kp) {
            bf16x8 pa;
            __builtin_amdgcn_s_setprio(1);
#pragma unroll
            for (int ch = 0; ch < 2; ++ch) {
                const int pr = kp * 32 + (lr >> 2) * 8 + ch * 4 + (lr & 3);
                const int hz = (pr & 3) | (((pr >> 3) & 1) << 2);
                bf16x8 k0 = *(const bf16x8*)&lds[buf * 4096 + pr * 64 + (lg ^ hz) * 8];
                bf16x8 k1 = *(const bf16x8*)&lds[buf * 4096 + pr * 64 + (((4 + lg) ^ hz)) * 8];
                f32x4 sb = __builtin_amdgcn_mfma_f32_16x16x32_bf16(k0, aq0, z0, 0, 0, 0);
                sb = __builtin_amdgcn_mfma_f32_16x16x32_bf16(k1, aq1, sb, 0, 0, 0);
                float4 p;
                p.x = exp2f(sb[0] * SCL) * invl;
                p.y = exp2f(sb[1] * SCL) * invl;
                p.z = exp2f(sb[2] * SCL) * invl;
                p.w = exp2f(sb[3] * SCL) * invl;
                *(float4*)(attn_base + kt * 64 + kp * 32 + lg * 8 + ch * 4) = p;
                pa[ch * 4 + 0] = (bf16_t)p.x;
                pa[ch * 4 + 1] = (bf16_t)p.y;
                pa[ch * 4 + 2] = (bf16_t)p.z;
                pa[ch * 4 + 3] = (bf16_t)p.w;
            }
#pragma unroll
            for (int nd = 0; nd < 4; ++nd) {
                const int vr = nd * 16 + lr;
                const int hv = (vr & 3) | (((vr >> 3) & 1) << 2);
                bf16x8 vb = *(const bf16x8*)&lds[(3 + buf) * 4096 + vr * 64 +
                                                 (((kp * 4 + lg) ^ hv)) * 8];
                cacc[nd] = __builtin_amdgcn_mfma_f32_16x16x32_bf16(pa, vb, cacc[nd], 0, 0, 0);
            }
            __builtin_amdgcn_s_setprio(0);
        }
        if (kt + 2 < 32) {
            const int nb = (kt + 2) % 3;
            STAGE_K(kt + 2, nb);
            STAGE_V(kt + 2, nb);
        }
    }
#pragma unroll
    for (int nd = 0; nd < 4; ++nd)
#pragma unroll
        for (int r = 0; r < 4; ++r)
            ctx[((size_t)b * Ss + q0 + lg * 4 + r) * 1024 + h * 64 + nd * 16 + lr] =
                (bf16_t)cacc[nd][r];
#undef STAGE_KA
#undef STAGE_K
#undef STAGE_V
}

// =====================  launcher  =====================
extern "C" void kernel_launch(void* const* d_in, const int* in_sizes, int n_in,
                              void* d_out, int out_size, void* d_ws, size_t ws_size,
                              hipStream_t stream) {
    const float* inp  = (const float*)d_in[0];
    const float* wq   = (const float*)d_in[1];
    const float* bq   = (const float*)d_in[2];
    const float* wk   = (const float*)d_in[3];
    const float* bk   = (const float*)d_in[4];
    const float* wv   = (const float*)d_in[5];
    const float* bv   = (const float*)d_in[6];
    const float* wo   = (const float*)d_in[7];
    const float* bo   = (const float*)d_in[8];
    const float* ln1g = (const float*)d_in[9];
    const float* ln1b = (const float*)d_in[10];
    const float* wi0  = (const float*)d_in[11];
    const float* bi0  = (const float*)d_in[12];
    const float* wi1  = (const float*)d_in[13];
    const float* bi1  = (const float*)d_in[14];
    const float* wff  = (const float*)d_in[15];
    const float* bff  = (const float*)d_in[16];
    const float* ln2g = (const float*)d_in[17];
    const float* ln2b = (const float*)d_in[18];

    // ---- workspace layout (152 MiB envelope, time-disjoint reuse) ----
    const size_t M1 = 1u << 20;
    bf16_t* wsb  = (bf16_t*)d_ws;
    bf16_t* wqT  = wsb + 0 * M1;
    bf16_t* wkT  = wsb + 1 * M1;
    bf16_t* wvT  = wsb + 2 * M1;
    bf16_t* woT  = wsb + 3 * M1;
    bf16_t* wi0T = wsb + 4 * M1;
    bf16_t* wi1T = wsb + 8 * M1;
    bf16_t* wffT = wsb + 12 * M1;
    bf16_t* hbuf = wsb + 16 * M1;            // LN out; dead after geglu
    bf16_t* qbuf = wsb + 20 * M1;
    bf16_t* kbuf = wsb + 24 * M1;
    bf16_t* vTb  = wsb + 28 * M1;            // [B,H,DK,S]
    bf16_t* ctxb = wsb + 32 * M1;            // dead after WO
    float*  h1   = (float*)(wsb + 36 * M1);  // 4M f32 (36M..44M slots)
    bf16_t* gbuf = wsb + 44 * M1;            // geglu out (44M..60M)
    float*  part = (float*)(wsb + 20 * M1);  // splitK partials (20M..36M; qkv/ctx dead)
    float*  cb   = (float*)(wsb + 60 * M1);  // qkv bias concat (consumed step 3)

    float* out  = (float*)d_out;
    float* attn = out + (size_t)TOK * Dd;

    // 1) all weights transposed->bf16 + qkv bias concat, one launch
    transpose_all<<<16385, 256, 0, stream>>>(wq, wk, wv, wo, wi0, wi1, wff,
                                             wqT, wkT, wvT, woT, wi0T, wi1T, wffT,
                                             bq, bk, bv, cb);

    // 2) LN1
    ln_fwd<<<TOK, 256, 0, stream>>>(inp, ln1g, ln1b, hbuf);

    // 3) fused QKV projection, 128x128 (768 blocks = 3/CU)
    gemm_t<128, 128, 3><<<dim3(24, 32), 256, 0, stream>>>(
        hbuf, wqT, cb, nullptr, qbuf, kbuf, vTb, TOK, 3072, 1024, 1024);

    // 4) fused attention (512 blocks x 8 waves)
    attn_fused<<<Bb * Hh * (Ss / 128), 512, 0, stream>>>(qbuf, kbuf, vTb, attn, ctxb);

    // 5) output projection + residual -> h1 (f32), 64x64 (1024 blocks)
    gemm_t<64, 64, 1><<<dim3(16, 64), 256, 0, stream>>>(
        ctxb, woT, bo, inp, h1, nullptr, nullptr, TOK, 1024, 1024, 1024);

    // 6) LN2
    ln_fwd<<<TOK, 256, 0, stream>>>(h1, ln2g, ln2b, hbuf);

    // 7) fused FFN-up + GeGLU -> gbuf (2048 blocks)
    gemm_geglu<<<dim3(64, 32), 256, 0, stream>>>(hbuf, wi0T, wi1T, bi0, bi1, gbuf);

    // 8) down projection 128x64, split-K=2 -> partials (1024 blocks = 4/CU)
    gemm_t<128, 64, 4><<<dim3(16, 32, 2), 256, 0, stream>>>(
        gbuf, wffT, bff, nullptr, part, nullptr, nullptr, TOK, 1024, 2048, 4096);

    // 9) reduce partials + bias + residual -> out
    reduce2<<<4096, 256, 0, stream>>>(part, h1, bff, out);
}

// Round 14
// 456.093 us; speedup vs baseline: 1.2600x; 1.0309x over previous
//
#include <hip/hip_runtime.h>
#include <hip/hip_bf16.h>
#include <cstdint>

#define DEV __device__ __forceinline__

typedef __bf16 bf16_t;
typedef __bf16 bf16x8 __attribute__((ext_vector_type(8)));
typedef __bf16 bf16x4 __attribute__((ext_vector_type(4)));
typedef float  f32x4  __attribute__((ext_vector_type(4)));

constexpr int Bb = 2, Ss = 2048, Dd = 1024, Hh = 16, DKk = 64, FFf = 4096;
constexpr int TOK = Bb * Ss;          // 4096 tokens
constexpr float LN_EPS = 1e-6f;

// ---- async global->LDS, 16B per lane (wave-uniform base + lane*16) ----
DEV void g2l16(const void* g, void* l) {
    __builtin_amdgcn_global_load_lds(
        (const __attribute__((address_space(1))) unsigned int*)g,
        (__attribute__((address_space(3))) unsigned int*)l, 16, 0, 0);
}

#define WAITCNT(N) asm volatile("s_waitcnt vmcnt(" #N ")" ::: "memory")
#define SCHEDB() __builtin_amdgcn_sched_barrier(0)

// ====  fused pre-pass: weights fp32->bf16 transposed + QKV bias + LN1  ======
// blocks [0,16384): weight transpose tiles; 16384: bias concat;
// blocks [16385, 16385+4096): LN1 rows (independent of transpose -> overlap).
__global__ __launch_bounds__(256)
void prepass(const float* __restrict__ wq, const float* __restrict__ wk,
             const float* __restrict__ wv, const float* __restrict__ wo,
             const float* __restrict__ wi0, const float* __restrict__ wi1,
             const float* __restrict__ wff,
             bf16_t* wqT, bf16_t* wkT, bf16_t* wvT, bf16_t* woT,
             bf16_t* wi0T, bf16_t* wi1T, bf16_t* wffT,
             const float* __restrict__ bq, const float* __restrict__ bk,
             const float* __restrict__ bv, float* __restrict__ cb,
             const float* __restrict__ x, const float* __restrict__ lg,
             const float* __restrict__ lb, bf16_t* __restrict__ lnout) {
    __shared__ float t[32][33];
    const int id = blockIdx.x;
    const int tid = threadIdx.x;
    if (id >= 16385) {                    // ---- LN1 row ----
        __shared__ float red[8];
        const int row = id - 16385;
        const float4 v = ((const float4*)(x + (size_t)row * Dd))[tid];
        float s  = v.x + v.y + v.z + v.w;
        float sq = v.x * v.x + v.y * v.y + v.z * v.z + v.w * v.w;
#pragma unroll
        for (int o = 32; o; o >>= 1) { s += __shfl_xor(s, o); sq += __shfl_xor(sq, o); }
        if ((tid & 63) == 0) { red[tid >> 6] = s; red[4 + (tid >> 6)] = sq; }
        __syncthreads();
        s  = red[0] + red[1] + red[2] + red[3];
        sq = red[4] + red[5] + red[6] + red[7];
        const float mean = s * (1.f / Dd);
        const float var  = sq * (1.f / Dd) - mean * mean;
        const float rs   = rsqrtf(var + LN_EPS);
        const float4 gv = ((const float4*)lg)[tid];
        const float4 bv2 = ((const float4*)lb)[tid];
        bf16x4 o4;
        o4[0] = (bf16_t)((v.x - mean) * rs * gv.x + bv2.x);
        o4[1] = (bf16_t)((v.y - mean) * rs * gv.y + bv2.y);
        o4[2] = (bf16_t)((v.z - mean) * rs * gv.z + bv2.z);
        o4[3] = (bf16_t)((v.w - mean) * rs * gv.w + bv2.w);
        ((bf16x4*)(lnout + (size_t)row * Dd))[tid] = o4;
        return;
    }
    if (id == 16384) {                    // ---- bias concat ----
#pragma unroll
        for (int i = 0; i < 4; ++i) {
            const int j = i * 256 + tid;
            cb[j] = bq[j]; cb[1024 + j] = bk[j]; cb[2048 + j] = bv[j];
        }
        return;
    }
    const float* src; bf16_t* dst; int K, N, tt;
    if (id < 4096) {
        const int w = id >> 10; tt = id & 1023; K = 1024; N = 1024;
        src = w == 0 ? wq : w == 1 ? wk : w == 2 ? wv : wo;
        dst = w == 0 ? wqT : w == 1 ? wkT : w == 2 ? wvT : woT;
    } else if (id < 12288) {
        const int w = (id - 4096) >> 12; tt = (id - 4096) & 4095; K = 1024; N = 4096;
        src = w ? wi1 : wi0; dst = w ? wi1T : wi0T;
    } else {
        tt = id - 12288; K = 4096; N = 1024;
        src = wff; dst = wffT;
    }
    const int ntn = N >> 5;
    const int n0 = (tt % ntn) * 32, k0 = (tt / ntn) * 32;
    const int tx = tid & 31, ty = tid >> 5;
#pragma unroll
    for (int i = 0; i < 4; ++i)
        t[ty + 8 * i][tx] = src[(size_t)(k0 + ty + 8 * i) * N + n0 + tx];
    __syncthreads();
#pragma unroll
    for (int i = 0; i < 4; ++i)
        dst[(size_t)(n0 + ty + 8 * i) * K + k0 + tx] = (bf16_t)t[tx][ty + 8 * i];
}

// =====================  LayerNorm fp32 -> bf16 (LN2)  =====================
__global__ __launch_bounds__(256)
void ln_fwd(const float* __restrict__ x, const float* __restrict__ g,
            const float* __restrict__ b, bf16_t* __restrict__ out) {
    __shared__ float red[8];
    const int row = blockIdx.x, tid = threadIdx.x;
    const float4 v = ((const float4*)(x + (size_t)row * Dd))[tid];
    float s  = v.x + v.y + v.z + v.w;
    float sq = v.x * v.x + v.y * v.y + v.z * v.z + v.w * v.w;
#pragma unroll
    for (int o = 32; o; o >>= 1) { s += __shfl_xor(s, o); sq += __shfl_xor(sq, o); }
    if ((tid & 63) == 0) { red[tid >> 6] = s; red[4 + (tid >> 6)] = sq; }
    __syncthreads();
    s  = red[0] + red[1] + red[2] + red[3];
    sq = red[4] + red[5] + red[6] + red[7];
    const float mean = s * (1.f / Dd);
    const float var  = sq * (1.f / Dd) - mean * mean;
    const float rs   = rsqrtf(var + LN_EPS);
    const float4 gv = ((const float4*)g)[tid];
    const float4 bv = ((const float4*)b)[tid];
    bf16x4 o4;
    o4[0] = (bf16_t)((v.x - mean) * rs * gv.x + bv.x);
    o4[1] = (bf16_t)((v.y - mean) * rs * gv.y + bv.y);
    o4[2] = (bf16_t)((v.z - mean) * rs * gv.z + bv.z);
    o4[3] = (bf16_t)((v.w - mean) * rs * gv.w + bv.w);
    ((bf16x4*)(out + (size_t)row * Dd))[tid] = o4;
}

// ---- shared GEMM epilogue (scalar paths) ----
template <int EPI>
DEV void gemm_epi(float val, int gr, int gc, int N, size_t zofs,
                  void* outp, void* out2, const float* resid) {
    if constexpr (EPI == 0) {
        ((bf16_t*)outp)[(size_t)gr * N + gc] = (bf16_t)val;
    } else if constexpr (EPI == 1) {
        const size_t idx = (size_t)gr * N + gc;
        ((float*)outp)[idx] = val + resid[idx];
    } else if constexpr (EPI == 4) {
        ((float*)outp)[zofs + (size_t)gr * N + gc] = val;   // split-K partial
    } else {
        // EPI==3 q/k part only (v handled by LDS bounce in kernel)
        const int sel = gc >> 10, col = gc & 1023;
        if (sel == 0) ((bf16_t*)outp)[(size_t)gr * 1024 + col] = (bf16_t)val;
        else          ((bf16_t*)out2)[(size_t)gr * 1024 + col] = (bf16_t)val;
    }
}

// =====================  GEMM: C = A[M,ld] @ Bt[N,ld]^T + bias  ==============
// EPI=3: fused QKV. v-blocks (n0 >= 2048) transpose their 128x128 tile via
// LDS (reusing As/Bs) and write vT coalesced along s (16B stores).
template <int BM, int BN, int EPI>
__global__ __launch_bounds__(256)
void gemm_t(const bf16_t* __restrict__ A, const bf16_t* __restrict__ Bt,
            const float* __restrict__ bias, const float* __restrict__ resid,
            void* __restrict__ outp, void* __restrict__ out2,
            void* __restrict__ out3, int M, int N, int K, int ld) {
    constexpr int WM = BM / 2, WN = BN / 2;
    constexpr int MI = WM / 16, NI = WN / 16;
    constexpr int CA = BM / 32, CB = BN / 32;
    __shared__ bf16_t sh[BM * 64 + BN * 64];
    bf16_t* As = sh;
    bf16_t* Bs = sh + BM * 64;
    const int tid = threadIdx.x;
    const int lane = tid & 63;
    const int wave = tid >> 6;
    const int wr = wave >> 1, wc = wave & 1;
    const int m0 = blockIdx.y * BM, n0 = blockIdx.x * BN;
    const int koff = blockIdx.z * K;
    const size_t zofs = (size_t)blockIdx.z * M * N;
    const int lr = lane & 15, lg = lane >> 4;

    const f32x4 z0 = {0.f, 0.f, 0.f, 0.f};
    f32x4 acc[MI][NI];
#pragma unroll
    for (int i = 0; i < MI; ++i)
#pragma unroll
        for (int j = 0; j < NI; ++j) acc[i][j] = z0;

    for (int k0 = 0; k0 < K; k0 += 64) {
#pragma unroll
        for (int c = 0; c < CA; ++c) {
            const int lin = c * 256 + tid;
            const int row = lin >> 3, col = (lin & 7) * 8;
            g2l16(A + (size_t)(m0 + row) * ld + koff + k0 + col, (char*)As + lin * 16);
        }
#pragma unroll
        for (int c = 0; c < CB; ++c) {
            const int lin = c * 256 + tid;
            const int row = lin >> 3, col = (lin & 7) * 8;
            g2l16(Bt + (size_t)(n0 + row) * ld + koff + k0 + col, (char*)Bs + lin * 16);
        }
        __syncthreads();

        bf16x8 af[2][MI], bw[2][NI];
#pragma unroll
        for (int kk = 0; kk < 2; ++kk)
#pragma unroll
            for (int mi = 0; mi < MI; ++mi)
                af[kk][mi] = *(const bf16x8*)(As + (wr * WM + mi * 16 + lr) * 64 +
                                              kk * 32 + lg * 8);
#pragma unroll
        for (int kk = 0; kk < 2; ++kk)
#pragma unroll
            for (int ni = 0; ni < NI; ++ni)
                bw[kk][ni] = *(const bf16x8*)(Bs + (wc * WN + ni * 16 + lr) * 64 +
                                              kk * 32 + lg * 8);
#pragma unroll
        for (int mi = 0; mi < MI; ++mi)
#pragma unroll
            for (int ni = 0; ni < NI; ++ni) {
                acc[mi][ni] = __builtin_amdgcn_mfma_f32_16x16x32_bf16(
                    af[0][mi], bw[0][ni], acc[mi][ni], 0, 0, 0);
                acc[mi][ni] = __builtin_amdgcn_mfma_f32_16x16x32_bf16(
                    af[1][mi], bw[1][ni], acc[mi][ni], 0, 0, 0);
            }
        __syncthreads();
    }

    if constexpr (EPI == 3) {
        if (n0 >= 2048 && BM == 128 && BN == 128) {
            // ---- v-block: LDS-bounce transpose, coalesced vT write ----
            bf16_t* tb = sh;   // 128 cols x 128 rows (16384 elems = 32KB)
#pragma unroll
            for (int mi = 0; mi < MI; ++mi)
#pragma unroll
                for (int ni = 0; ni < NI; ++ni) {
                    const int cl = wc * WN + ni * 16 + lr;        // col-local
                    const int rl0 = wr * WM + mi * 16 + lg * 4;   // row-local
                    const float bvl = bias[n0 + cl];
#pragma unroll
                    for (int r = 0; r < 4; ++r)
                        tb[cl * 128 + rl0 + r] = (bf16_t)(acc[mi][ni][r] + bvl);
                }
            __syncthreads();
            // write: vT[b, col, s]; block's 128 rows = one b, s0..s0+128
            const int bb = m0 >> 11, s0 = m0 & 2047;
            bf16_t* vout = (bf16_t*)out3 + ((size_t)bb << 21) + ((size_t)(n0 - 2048) << 11) + s0;
            const int cl = tid >> 4;            // 16 cols per round
            const int sc = (tid & 15) * 8;      // 8 s-elems per thread
#pragma unroll
            for (int rnd = 0; rnd < 8; ++rnd) {
                const int c = rnd * 16 + cl;
                *(bf16x8*)(vout + ((size_t)c << 11) + sc) =
                    *(const bf16x8*)(tb + c * 128 + sc);
            }
            return;
        }
    }

#pragma unroll
    for (int mi = 0; mi < MI; ++mi)
#pragma unroll
        for (int ni = 0; ni < NI; ++ni) {
            const int gc = n0 + wc * WN + ni * 16 + lr;
            const int gr0 = m0 + wr * WM + mi * 16 + lg * 4;
            const float bvl = (EPI == 4) ? 0.f : bias[gc];
#pragma unroll
            for (int r = 0; r < 4; ++r)
                gemm_epi<EPI>(acc[mi][ni][r] + bvl, gr0 + r, gc, N, zofs,
                              outp, out2, resid);
        }
}

// =====================  split-K=2 reduce: out = p0+p1+bff+h1  ================
__global__ __launch_bounds__(256)
void reduce2(const float* __restrict__ part, const float* __restrict__ h1,
             const float* __restrict__ bff, float* __restrict__ out) {
    const int row = blockIdx.x, tid = threadIdx.x;
    const size_t idx = (size_t)row * 1024 + tid * 4;
    const float4 a = *(const float4*)(part + idx);
    const float4 b = *(const float4*)(part + (size_t)4096 * 1024 + idx);
    const float4 r = *(const float4*)(h1 + idx);
    const float4 bv = *(const float4*)(bff + tid * 4);
    float4 o;
    o.x = a.x + b.x + r.x + bv.x;
    o.y = a.y + b.y + r.y + bv.y;
    o.z = a.z + b.z + r.z + bv.z;
    o.w = a.w + b.w + r.w + bv.w;
    *(float4*)(out + idx) = o;
}

// =====================  fused FFN-up + GeGLU (unchanged)  ====================
__global__ __launch_bounds__(256)
void gemm_geglu(const bf16_t* __restrict__ A, const bf16_t* __restrict__ Bg,
                const bf16_t* __restrict__ Bl, const float* __restrict__ bi0,
                const float* __restrict__ bi1, bf16_t* __restrict__ gout) {
    __shared__ bf16_t As[128 * 64];
    __shared__ bf16_t Bgs[64 * 64];
    __shared__ bf16_t Bls[64 * 64];
    const int tid = threadIdx.x;
    const int lane = tid & 63;
    const int wave = tid >> 6;
    const int wr = wave >> 1, wc = wave & 1;
    const int m0 = blockIdx.y * 128, n0 = blockIdx.x * 64;
    const int lr = lane & 15, lg = lane >> 4;

    const f32x4 z0 = {0.f, 0.f, 0.f, 0.f};
    f32x4 ag[4][2], al[4][2];
#pragma unroll
    for (int i = 0; i < 4; ++i)
#pragma unroll
        for (int j = 0; j < 2; ++j) { ag[i][j] = z0; al[i][j] = z0; }

    for (int k0 = 0; k0 < 1024; k0 += 64) {
#pragma unroll
        for (int c = 0; c < 4; ++c) {
            const int lin = c * 256 + tid;
            const int row = lin >> 3, col = (lin & 7) * 8;
            g2l16(A + (size_t)(m0 + row) * 1024 + k0 + col, (char*)As + lin * 16);
        }
#pragma unroll
        for (int c = 0; c < 2; ++c) {
            const int lin = c * 256 + tid;
            const int row = lin >> 3, col = (lin & 7) * 8;
            g2l16(Bg + (size_t)(n0 + row) * 1024 + k0 + col, (char*)Bgs + lin * 16);
        }
#pragma unroll
        for (int c = 0; c < 2; ++c) {
            const int lin = c * 256 + tid;
            const int row = lin >> 3, col = (lin & 7) * 8;
            g2l16(Bl + (size_t)(n0 + row) * 1024 + k0 + col, (char*)Bls + lin * 16);
        }
        __syncthreads();

        bf16x8 af[2][4], bg[2][2], bl[2][2];
#pragma unroll
        for (int kk = 0; kk < 2; ++kk) {
#pragma unroll
            for (int mi = 0; mi < 4; ++mi)
                af[kk][mi] = *(const bf16x8*)(As + (wr * 64 + mi * 16 + lr) * 64 +
                                              kk * 32 + lg * 8);
#pragma unroll
            for (int ni = 0; ni < 2; ++ni) {
                bg[kk][ni] = *(const bf16x8*)(Bgs + (wc * 32 + ni * 16 + lr) * 64 +
                                              kk * 32 + lg * 8);
                bl[kk][ni] = *(const bf16x8*)(Bls + (wc * 32 + ni * 16 + lr) * 64 +
                                              kk * 32 + lg * 8);
            }
        }
#pragma unroll
        for (int mi = 0; mi < 4; ++mi)
#pragma unroll
            for (int ni = 0; ni < 2; ++ni) {
#pragma unroll
                for (int kk = 0; kk < 2; ++kk) {
                    ag[mi][ni] = __builtin_amdgcn_mfma_f32_16x16x32_bf16(
                        af[kk][mi], bg[kk][ni], ag[mi][ni], 0, 0, 0);
                    al[mi][ni] = __builtin_amdgcn_mfma_f32_16x16x32_bf16(
                        af[kk][mi], bl[kk][ni], al[mi][ni], 0, 0, 0);
                }
            }
        __syncthreads();
    }

#pragma unroll
    for (int mi = 0; mi < 4; ++mi)
#pragma unroll
        for (int ni = 0; ni < 2; ++ni) {
            const int gc = n0 + wc * 32 + ni * 16 + lr;
            const int gr0 = m0 + wr * 64 + mi * 16 + lg * 4;
            const float b0 = bi0[gc], b1 = bi1[gc];
#pragma unroll
            for (int r = 0; r < 4; ++r) {
                const float x = ag[mi][ni][r] + b0;
                const float y = al[mi][ni][r] + b1;
                const float ge = 0.5f * x * (1.f + erff(x * 0.70710678118654752f));
                gout[(size_t)(gr0 + r) * 4096 + gc] = (bf16_t)(ge * y);
            }
        }
}

// ======  fused attention v8 (round-13 proven, unchanged)  ====================
__global__ __launch_bounds__(512)
void attn_fused(const bf16_t* __restrict__ q, const bf16_t* __restrict__ k,
                const bf16_t* __restrict__ vT, float* __restrict__ attn,
                bf16_t* __restrict__ ctx) {
    __shared__ bf16_t lds[6 * 4096];
    const int tid = threadIdx.x, lane = tid & 63, wave = tid >> 6;   // 8 waves
    const int lr = lane & 15, lg = lane >> 4;
    int blk = blockIdx.x;
    blk = (blk & 7) * 64 + (blk >> 3);       // XCD swizzle (512 % 8 == 0)
    const int qc = blk & 15, bh = blk >> 4;
    const int b = bh >> 4, h = bh & 15;
    const int q0 = qc * 128 + wave * 16;
    const size_t base = (size_t)b * (Ss * 1024) + h * 64;
    constexpr float SCL = 0.125f * 1.4426950408889634f;   // 1/sqrt(64) * log2(e)
    const f32x4 z0 = {0.f, 0.f, 0.f, 0.f};

    const int st_r8 = lane >> 3;
    const int st_c0 = (lane & 7) ^ (st_r8 & 3) ^ ((wave & 1) << 2);
    const int st_c0A = (lane & 7) ^ (st_r8 & 3);

    const bf16x8 aq0 = *(const bf16x8*)(q + base + (size_t)(q0 + lr) * 1024 + lg * 8);
    const bf16x8 aq1 = *(const bf16x8*)(q + base + (size_t)(q0 + lr) * 1024 + 32 + lg * 8);
    const bf16_t* kb = k + base;
    const bf16_t* vb_base = vT + ((size_t)bh * 64) * Ss;

#define STAGE_KA(kt_, buf_)                                                       \
    {                                                                             \
        g2l16(kb + (size_t)((kt_) * 128 + wave * 16 + st_r8) * 1024 + st_c0A * 8, \
              lds + (buf_) * 8192 + wave * 1024);                                 \
        g2l16(kb + (size_t)((kt_) * 128 + wave * 16 + 8 + st_r8) * 1024 +         \
                  (st_c0A ^ 4) * 8,                                               \
              lds + (buf_) * 8192 + wave * 1024 + 512);                           \
    }
#define STAGE_K(kt_, buf_)                                                        \
    g2l16(kb + (size_t)((kt_) * 64 + wave * 8 + st_r8) * 1024 + st_c0 * 8,        \
          lds + (buf_) * 4096 + wave * 512);
#define STAGE_V(kt_, buf_)                                                        \
    g2l16(vb_base + (size_t)(wave * 8 + st_r8) * Ss + (kt_) * 64 + st_c0 * 8,     \
          lds + (3 + (buf_)) * 4096 + wave * 512);

    // ---- pass A: esum over 16 tiles of 128 k-rows ----
    f32x4 ea = z0, eb = z0;
    STAGE_KA(0, 0);
    STAGE_KA(1, 1);
    for (int kt = 0; kt < 16; ++kt) {
        const int buf = kt % 3;
        if (kt == 15) { WAITCNT(0); } else { WAITCNT(2); }
        SCHEDB();
        __builtin_amdgcn_s_barrier();
        SCHEDB();
        f32x4 sa[8];
        __builtin_amdgcn_s_setprio(1);
#pragma unroll
        for (int ct = 0; ct < 8; ++ct) {
            const int ar = ct * 16 + lr;
            const int hz = (ar & 3) | (((ar >> 3) & 1) << 2);
            bf16x8 k0 = *(const bf16x8*)&lds[buf * 8192 + ar * 64 + (lg ^ hz) * 8];
            bf16x8 k1 = *(const bf16x8*)&lds[buf * 8192 + ar * 64 + (((4 + lg) ^ hz)) * 8];
            sa[ct] = __builtin_amdgcn_mfma_f32_16x16x32_bf16(k0, aq0, z0, 0, 0, 0);
            sa[ct] = __builtin_amdgcn_mfma_f32_16x16x32_bf16(k1, aq1, sa[ct], 0, 0, 0);
        }
        __builtin_amdgcn_s_setprio(0);
#pragma unroll
        for (int r = 0; r < 4; ++r) {
            ea[r] += exp2f(sa[0][r] * SCL) + exp2f(sa[1][r] * SCL) +
                     exp2f(sa[2][r] * SCL) + exp2f(sa[3][r] * SCL);
            eb[r] += exp2f(sa[4][r] * SCL) + exp2f(sa[5][r] * SCL) +
                     exp2f(sa[6][r] * SCL) + exp2f(sa[7][r] * SCL);
        }
        if (kt + 2 < 16) STAGE_KA(kt + 2, (kt + 2) % 3);
    }
    float e = ((ea[0] + ea[1]) + (ea[2] + ea[3])) + ((eb[0] + eb[1]) + (eb[2] + eb[3]));
    e += __shfl_xor(e, 16);
    e += __shfl_xor(e, 32);
    const float invl = 1.f / e;

    f32x4 cacc[4];
#pragma unroll
    for (int nd = 0; nd < 4; ++nd) cacc[nd] = z0;

    float* attn_base = attn + ((size_t)bh * Ss + q0 + lr) * Ss;

    __builtin_amdgcn_s_barrier();   // all waves done reading pass-A buffers
    SCHEDB();

    // ---- pass B (round-9 proven schedule) ----
    STAGE_K(0, 0); STAGE_V(0, 0);
    STAGE_K(1, 1); STAGE_V(1, 1);
    for (int kt = 0; kt < 32; ++kt) {
        const int buf = kt % 3;
        if (kt == 0) { WAITCNT(2); }
        else if (kt == 31) { WAITCNT(4); }
        else { WAITCNT(6); }
        SCHEDB();
        __builtin_amdgcn_s_barrier();
        SCHEDB();
#pragma unroll
        for (int kp = 0; kp < 2; ++kp) {
            bf16x8 pa;
            __builtin_amdgcn_s_setprio(1);
#pragma unroll
            for (int ch = 0; ch < 2; ++ch) {
                const int pr = kp * 32 + (lr >> 2) * 8 + ch * 4 + (lr & 3);
                const int hz = (pr & 3) | (((pr >> 3) & 1) << 2);
                bf16x8 k0 = *(const bf16x8*)&lds[buf * 4096 + pr * 64 + (lg ^ hz) * 8];
                bf16x8 k1 = *(const bf16x8*)&lds[buf * 4096 + pr * 64 + (((4 + lg) ^ hz)) * 8];
                f32x4 sb = __builtin_amdgcn_mfma_f32_16x16x32_bf16(k0, aq0, z0, 0, 0, 0);
                sb = __builtin_amdgcn_mfma_f32_16x16x32_bf16(k1, aq1, sb, 0, 0, 0);
                float4 p;
                p.x = exp2f(sb[0] * SCL) * invl;
                p.y = exp2f(sb[1] * SCL) * invl;
                p.z = exp2f(sb[2] * SCL) * invl;
                p.w = exp2f(sb[3] * SCL) * invl;
                *(float4*)(attn_base + kt * 64 + kp * 32 + lg * 8 + ch * 4) = p;
                pa[ch * 4 + 0] = (bf16_t)p.x;
                pa[ch * 4 + 1] = (bf16_t)p.y;
                pa[ch * 4 + 2] = (bf16_t)p.z;
                pa[ch * 4 + 3] = (bf16_t)p.w;
            }
#pragma unroll
            for (int nd = 0; nd < 4; ++nd) {
                const int vr = nd * 16 + lr;
                const int hv = (vr & 3) | (((vr >> 3) & 1) << 2);
                bf16x8 vb = *(const bf16x8*)&lds[(3 + buf) * 4096 + vr * 64 +
                                                 (((kp * 4 + lg) ^ hv)) * 8];
                cacc[nd] = __builtin_amdgcn_mfma_f32_16x16x32_bf16(pa, vb, cacc[nd], 0, 0, 0);
            }
            __builtin_amdgcn_s_setprio(0);
        }
        if (kt + 2 < 32) {
            const int nb = (kt + 2) % 3;
            STAGE_K(kt + 2, nb);
            STAGE_V(kt + 2, nb);
        }
    }
#pragma unroll
    for (int nd = 0; nd < 4; ++nd)
#pragma unroll
        for (int r = 0; r < 4; ++r)
            ctx[((size_t)b * Ss + q0 + lg * 4 + r) * 1024 + h * 64 + nd * 16 + lr] =
                (bf16_t)cacc[nd][r];
#undef STAGE_KA
#undef STAGE_K
#undef STAGE_V
}

// =====================  launcher  =====================
extern "C" void kernel_launch(void* const* d_in, const int* in_sizes, int n_in,
                              void* d_out, int out_size, void* d_ws, size_t ws_size,
                              hipStream_t stream) {
    const float* inp  = (const float*)d_in[0];
    const float* wq   = (const float*)d_in[1];
    const float* bq   = (const float*)d_in[2];
    const float* wk   = (const float*)d_in[3];
    const float* bk   = (const float*)d_in[4];
    const float* wv   = (const float*)d_in[5];
    const float* bv   = (const float*)d_in[6];
    const float* wo   = (const float*)d_in[7];
    const float* bo   = (const float*)d_in[8];
    const float* ln1g = (const float*)d_in[9];
    const float* ln1b = (const float*)d_in[10];
    const float* wi0  = (const float*)d_in[11];
    const float* bi0  = (const float*)d_in[12];
    const float* wi1  = (const float*)d_in[13];
    const float* bi1  = (const float*)d_in[14];
    const float* wff  = (const float*)d_in[15];
    const float* bff  = (const float*)d_in[16];
    const float* ln2g = (const float*)d_in[17];
    const float* ln2b = (const float*)d_in[18];

    // ---- workspace layout (152 MiB envelope, time-disjoint reuse) ----
    const size_t M1 = 1u << 20;
    bf16_t* wsb  = (bf16_t*)d_ws;
    bf16_t* wqT  = wsb + 0 * M1;
    bf16_t* wkT  = wsb + 1 * M1;
    bf16_t* wvT  = wsb + 2 * M1;
    bf16_t* woT  = wsb + 3 * M1;
    bf16_t* wi0T = wsb + 4 * M1;
    bf16_t* wi1T = wsb + 8 * M1;
    bf16_t* wffT = wsb + 12 * M1;
    bf16_t* hbuf = wsb + 16 * M1;            // LN out; dead after geglu
    bf16_t* qbuf = wsb + 20 * M1;
    bf16_t* kbuf = wsb + 24 * M1;
    bf16_t* vTb  = wsb + 28 * M1;            // [B,H,DK,S]
    bf16_t* ctxb = wsb + 32 * M1;            // dead after WO
    float*  h1   = (float*)(wsb + 36 * M1);  // 4M f32 (36M..44M slots)
    bf16_t* gbuf = wsb + 44 * M1;            // geglu out (44M..60M)
    float*  part = (float*)(wsb + 20 * M1);  // splitK partials (20M..36M; qkv/ctx dead)
    float*  cb   = (float*)(wsb + 60 * M1);  // qkv bias concat (consumed step 2)

    float* out  = (float*)d_out;
    float* attn = out + (size_t)TOK * Dd;

    // 1) weights transpose + qkv bias concat + LN1, one launch (overlapped)
    prepass<<<16385 + TOK, 256, 0, stream>>>(wq, wk, wv, wo, wi0, wi1, wff,
                                             wqT, wkT, wvT, woT, wi0T, wi1T, wffT,
                                             bq, bk, bv, cb,
                                             inp, ln1g, ln1b, hbuf);

    // 2) fused QKV projection, 128x128 (768 blocks = 3/CU); v via LDS bounce
    gemm_t<128, 128, 3><<<dim3(24, 32), 256, 0, stream>>>(
        hbuf, wqT, cb, nullptr, qbuf, kbuf, vTb, TOK, 3072, 1024, 1024);

    // 3) fused attention (512 blocks x 8 waves)
    attn_fused<<<Bb * Hh * (Ss / 128), 512, 0, stream>>>(qbuf, kbuf, vTb, attn, ctxb);

    // 4) output projection + residual -> h1 (f32), 64x64 (1024 blocks)
    gemm_t<64, 64, 1><<<dim3(16, 64), 256, 0, stream>>>(
        ctxb, woT, bo, inp, h1, nullptr, nullptr, TOK, 1024, 1024, 1024);

    // 5) LN2
    ln_fwd<<<TOK, 256, 0, stream>>>(h1, ln2g, ln2b, hbuf);

    // 6) fused FFN-up + GeGLU -> gbuf (2048 blocks)
    gemm_geglu<<<dim3(64, 32), 256, 0, stream>>>(hbuf, wi0T, wi1T, bi0, bi1, gbuf);

    // 7) down projection 128x64, split-K=2 -> partials (1024 blocks = 4/CU)
    gemm_t<128, 64, 4><<<dim3(16, 32, 2), 256, 0, stream>>>(
        gbuf, wffT, bff, nullptr, part, nullptr, nullptr, TOK, 1024, 2048, 4096);

    // 8) reduce partials + bias + residual -> out
    reduce2<<<4096, 256, 0, stream>>>(part, h1, bff, out);
}

// Round 15
// 446.952 us; speedup vs baseline: 1.2858x; 1.0205x over previous
//
#include <hip/hip_runtime.h>
#include <hip/hip_bf16.h>
#include <cstdint>

#define DEV __device__ __forceinline__

typedef __bf16 bf16_t;
typedef __bf16 bf16x8 __attribute__((ext_vector_type(8)));
typedef __bf16 bf16x4 __attribute__((ext_vector_type(4)));
typedef float  f32x4  __attribute__((ext_vector_type(4)));

constexpr int Bb = 2, Ss = 2048, Dd = 1024, Hh = 16, DKk = 64, FFf = 4096;
constexpr int TOK = Bb * Ss;          // 4096 tokens
constexpr float LN_EPS = 1e-6f;

// ---- async global->LDS, 16B per lane (wave-uniform base + lane*16) ----
DEV void g2l16(const void* g, void* l) {
    __builtin_amdgcn_global_load_lds(
        (const __attribute__((address_space(1))) unsigned int*)g,
        (__attribute__((address_space(3))) unsigned int*)l, 16, 0, 0);
}

#define WAITCNT(N) asm volatile("s_waitcnt vmcnt(" #N ")" ::: "memory")
#define SCHEDB() __builtin_amdgcn_sched_barrier(0)

// ====  fused pre-pass: weights fp32->bf16 transposed + QKV bias + LN1  ======
__global__ __launch_bounds__(256)
void prepass(const float* __restrict__ wq, const float* __restrict__ wk,
             const float* __restrict__ wv, const float* __restrict__ wo,
             const float* __restrict__ wi0, const float* __restrict__ wi1,
             const float* __restrict__ wff,
             bf16_t* wqT, bf16_t* wkT, bf16_t* wvT, bf16_t* woT,
             bf16_t* wi0T, bf16_t* wi1T, bf16_t* wffT,
             const float* __restrict__ bq, const float* __restrict__ bk,
             const float* __restrict__ bv, float* __restrict__ cb,
             const float* __restrict__ x, const float* __restrict__ lg,
             const float* __restrict__ lb, bf16_t* __restrict__ lnout) {
    __shared__ float t[32][33];
    const int id = blockIdx.x;
    const int tid = threadIdx.x;
    if (id >= 16385) {                    // ---- LN1 row ----
        __shared__ float red[8];
        const int row = id - 16385;
        const float4 v = ((const float4*)(x + (size_t)row * Dd))[tid];
        float s  = v.x + v.y + v.z + v.w;
        float sq = v.x * v.x + v.y * v.y + v.z * v.z + v.w * v.w;
#pragma unroll
        for (int o = 32; o; o >>= 1) { s += __shfl_xor(s, o); sq += __shfl_xor(sq, o); }
        if ((tid & 63) == 0) { red[tid >> 6] = s; red[4 + (tid >> 6)] = sq; }
        __syncthreads();
        s  = red[0] + red[1] + red[2] + red[3];
        sq = red[4] + red[5] + red[6] + red[7];
        const float mean = s * (1.f / Dd);
        const float var  = sq * (1.f / Dd) - mean * mean;
        const float rs   = rsqrtf(var + LN_EPS);
        const float4 gv = ((const float4*)lg)[tid];
        const float4 bv2 = ((const float4*)lb)[tid];
        bf16x4 o4;
        o4[0] = (bf16_t)((v.x - mean) * rs * gv.x + bv2.x);
        o4[1] = (bf16_t)((v.y - mean) * rs * gv.y + bv2.y);
        o4[2] = (bf16_t)((v.z - mean) * rs * gv.z + bv2.z);
        o4[3] = (bf16_t)((v.w - mean) * rs * gv.w + bv2.w);
        ((bf16x4*)(lnout + (size_t)row * Dd))[tid] = o4;
        return;
    }
    if (id == 16384) {                    // ---- bias concat ----
#pragma unroll
        for (int i = 0; i < 4; ++i) {
            const int j = i * 256 + tid;
            cb[j] = bq[j]; cb[1024 + j] = bk[j]; cb[2048 + j] = bv[j];
        }
        return;
    }
    const float* src; bf16_t* dst; int K, N, tt;
    if (id < 4096) {
        const int w = id >> 10; tt = id & 1023; K = 1024; N = 1024;
        src = w == 0 ? wq : w == 1 ? wk : w == 2 ? wv : wo;
        dst = w == 0 ? wqT : w == 1 ? wkT : w == 2 ? wvT : woT;
    } else if (id < 12288) {
        const int w = (id - 4096) >> 12; tt = (id - 4096) & 4095; K = 1024; N = 4096;
        src = w ? wi1 : wi0; dst = w ? wi1T : wi0T;
    } else {
        tt = id - 12288; K = 4096; N = 1024;
        src = wff; dst = wffT;
    }
    const int ntn = N >> 5;
    const int n0 = (tt % ntn) * 32, k0 = (tt / ntn) * 32;
    const int tx = tid & 31, ty = tid >> 5;
#pragma unroll
    for (int i = 0; i < 4; ++i)
        t[ty + 8 * i][tx] = src[(size_t)(k0 + ty + 8 * i) * N + n0 + tx];
    __syncthreads();
#pragma unroll
    for (int i = 0; i < 4; ++i)
        dst[(size_t)(n0 + ty + 8 * i) * K + k0 + tx] = (bf16_t)t[tx][ty + 8 * i];
}

// =====================  LayerNorm fp32 -> bf16 (LN2)  =====================
__global__ __launch_bounds__(256)
void ln_fwd(const float* __restrict__ x, const float* __restrict__ g,
            const float* __restrict__ b, bf16_t* __restrict__ out) {
    __shared__ float red[8];
    const int row = blockIdx.x, tid = threadIdx.x;
    const float4 v = ((const float4*)(x + (size_t)row * Dd))[tid];
    float s  = v.x + v.y + v.z + v.w;
    float sq = v.x * v.x + v.y * v.y + v.z * v.z + v.w * v.w;
#pragma unroll
    for (int o = 32; o; o >>= 1) { s += __shfl_xor(s, o); sq += __shfl_xor(sq, o); }
    if ((tid & 63) == 0) { red[tid >> 6] = s; red[4 + (tid >> 6)] = sq; }
    __syncthreads();
    s  = red[0] + red[1] + red[2] + red[3];
    sq = red[4] + red[5] + red[6] + red[7];
    const float mean = s * (1.f / Dd);
    const float var  = sq * (1.f / Dd) - mean * mean;
    const float rs   = rsqrtf(var + LN_EPS);
    const float4 gv = ((const float4*)g)[tid];
    const float4 bv = ((const float4*)b)[tid];
    bf16x4 o4;
    o4[0] = (bf16_t)((v.x - mean) * rs * gv.x + bv.x);
    o4[1] = (bf16_t)((v.y - mean) * rs * gv.y + bv.y);
    o4[2] = (bf16_t)((v.z - mean) * rs * gv.z + bv.z);
    o4[3] = (bf16_t)((v.w - mean) * rs * gv.w + bv.w);
    ((bf16x4*)(out + (size_t)row * Dd))[tid] = o4;
}

// ---- shared GEMM epilogue (scalar paths) ----
template <int EPI>
DEV void gemm_epi(float val, int gr, int gc, int N, size_t zofs,
                  void* outp, void* out2, const float* resid) {
    if constexpr (EPI == 0) {
        ((bf16_t*)outp)[(size_t)gr * N + gc] = (bf16_t)val;
    } else if constexpr (EPI == 1) {
        const size_t idx = (size_t)gr * N + gc;
        ((float*)outp)[idx] = val + resid[idx];
    } else if constexpr (EPI == 4) {
        ((float*)outp)[zofs + (size_t)gr * N + gc] = val;   // split-K partial
    } else {
        const int sel = gc >> 10, col = gc & 1023;
        if (sel == 0) ((bf16_t*)outp)[(size_t)gr * 1024 + col] = (bf16_t)val;
        else          ((bf16_t*)out2)[(size_t)gr * 1024 + col] = (bf16_t)val;
    }
}

// =====================  GEMM: C = A[M,ld] @ Bt[N,ld]^T + bias  ==============
template <int BM, int BN, int EPI>
__global__ __launch_bounds__(256)
void gemm_t(const bf16_t* __restrict__ A, const bf16_t* __restrict__ Bt,
            const float* __restrict__ bias, const float* __restrict__ resid,
            void* __restrict__ outp, void* __restrict__ out2,
            void* __restrict__ out3, int M, int N, int K, int ld) {
    constexpr int WM = BM / 2, WN = BN / 2;
    constexpr int MI = WM / 16, NI = WN / 16;
    constexpr int CA = BM / 32, CB = BN / 32;
    __shared__ bf16_t sh[BM * 64 + BN * 64];
    bf16_t* As = sh;
    bf16_t* Bs = sh + BM * 64;
    const int tid = threadIdx.x;
    const int lane = tid & 63;
    const int wave = tid >> 6;
    const int wr = wave >> 1, wc = wave & 1;
    const int m0 = blockIdx.y * BM, n0 = blockIdx.x * BN;
    const int koff = blockIdx.z * K;
    const size_t zofs = (size_t)blockIdx.z * M * N;
    const int lr = lane & 15, lg = lane >> 4;

    const f32x4 z0 = {0.f, 0.f, 0.f, 0.f};
    f32x4 acc[MI][NI];
#pragma unroll
    for (int i = 0; i < MI; ++i)
#pragma unroll
        for (int j = 0; j < NI; ++j) acc[i][j] = z0;

    for (int k0 = 0; k0 < K; k0 += 64) {
#pragma unroll
        for (int c = 0; c < CA; ++c) {
            const int lin = c * 256 + tid;
            const int row = lin >> 3, col = (lin & 7) * 8;
            g2l16(A + (size_t)(m0 + row) * ld + koff + k0 + col, (char*)As + lin * 16);
        }
#pragma unroll
        for (int c = 0; c < CB; ++c) {
            const int lin = c * 256 + tid;
            const int row = lin >> 3, col = (lin & 7) * 8;
            g2l16(Bt + (size_t)(n0 + row) * ld + koff + k0 + col, (char*)Bs + lin * 16);
        }
        __syncthreads();

        bf16x8 af[2][MI], bw[2][NI];
#pragma unroll
        for (int kk = 0; kk < 2; ++kk)
#pragma unroll
            for (int mi = 0; mi < MI; ++mi)
                af[kk][mi] = *(const bf16x8*)(As + (wr * WM + mi * 16 + lr) * 64 +
                                              kk * 32 + lg * 8);
#pragma unroll
        for (int kk = 0; kk < 2; ++kk)
#pragma unroll
            for (int ni = 0; ni < NI; ++ni)
                bw[kk][ni] = *(const bf16x8*)(Bs + (wc * WN + ni * 16 + lr) * 64 +
                                              kk * 32 + lg * 8);
#pragma unroll
        for (int mi = 0; mi < MI; ++mi)
#pragma unroll
            for (int ni = 0; ni < NI; ++ni) {
                acc[mi][ni] = __builtin_amdgcn_mfma_f32_16x16x32_bf16(
                    af[0][mi], bw[0][ni], acc[mi][ni], 0, 0, 0);
                acc[mi][ni] = __builtin_amdgcn_mfma_f32_16x16x32_bf16(
                    af[1][mi], bw[1][ni], acc[mi][ni], 0, 0, 0);
            }
        __syncthreads();
    }

    if constexpr (EPI == 3) {
        if (n0 >= 2048 && BM == 128 && BN == 128) {
            // ---- v-block: LDS-bounce transpose, coalesced vT write ----
            bf16_t* tb = sh;
#pragma unroll
            for (int mi = 0; mi < MI; ++mi)
#pragma unroll
                for (int ni = 0; ni < NI; ++ni) {
                    const int cl = wc * WN + ni * 16 + lr;
                    const int rl0 = wr * WM + mi * 16 + lg * 4;
                    const float bvl = bias[n0 + cl];
#pragma unroll
                    for (int r = 0; r < 4; ++r)
                        tb[cl * 128 + rl0 + r] = (bf16_t)(acc[mi][ni][r] + bvl);
                }
            __syncthreads();
            const int bb = m0 >> 11, s0 = m0 & 2047;
            bf16_t* vout = (bf16_t*)out3 + ((size_t)bb << 21) + ((size_t)(n0 - 2048) << 11) + s0;
            const int cl = tid >> 4;
            const int sc = (tid & 15) * 8;
#pragma unroll
            for (int rnd = 0; rnd < 8; ++rnd) {
                const int c = rnd * 16 + cl;
                *(bf16x8*)(vout + ((size_t)c << 11) + sc) =
                    *(const bf16x8*)(tb + c * 128 + sc);
            }
            return;
        }
    }

#pragma unroll
    for (int mi = 0; mi < MI; ++mi)
#pragma unroll
        for (int ni = 0; ni < NI; ++ni) {
            const int gc = n0 + wc * WN + ni * 16 + lr;
            const int gr0 = m0 + wr * WM + mi * 16 + lg * 4;
            const float bvl = (EPI == 4) ? 0.f : bias[gc];
#pragma unroll
            for (int r = 0; r < 4; ++r)
                gemm_epi<EPI>(acc[mi][ni][r] + bvl, gr0 + r, gc, N, zofs,
                              outp, out2, resid);
        }
}

// =====================  split-K=2 reduce: out = p0+p1+bff+h1  ================
__global__ __launch_bounds__(256)
void reduce2(const float* __restrict__ part, const float* __restrict__ h1,
             const float* __restrict__ bff, float* __restrict__ out) {
    const int row = blockIdx.x, tid = threadIdx.x;
    const size_t idx = (size_t)row * 1024 + tid * 4;
    const float4 a = *(const float4*)(part + idx);
    const float4 b = *(const float4*)(part + (size_t)4096 * 1024 + idx);
    const float4 r = *(const float4*)(h1 + idx);
    const float4 bv = *(const float4*)(bff + tid * 4);
    float4 o;
    o.x = a.x + b.x + r.x + bv.x;
    o.y = a.y + b.y + r.y + bv.y;
    o.z = a.z + b.z + r.z + bv.z;
    o.w = a.w + b.w + r.w + bv.w;
    *(float4*)(out + idx) = o;
}

// =====================  fused FFN-up + GeGLU (unchanged)  ====================
__global__ __launch_bounds__(256)
void gemm_geglu(const bf16_t* __restrict__ A, const bf16_t* __restrict__ Bg,
                const bf16_t* __restrict__ Bl, const float* __restrict__ bi0,
                const float* __restrict__ bi1, bf16_t* __restrict__ gout) {
    __shared__ bf16_t As[128 * 64];
    __shared__ bf16_t Bgs[64 * 64];
    __shared__ bf16_t Bls[64 * 64];
    const int tid = threadIdx.x;
    const int lane = tid & 63;
    const int wave = tid >> 6;
    const int wr = wave >> 1, wc = wave & 1;
    const int m0 = blockIdx.y * 128, n0 = blockIdx.x * 64;
    const int lr = lane & 15, lg = lane >> 4;

    const f32x4 z0 = {0.f, 0.f, 0.f, 0.f};
    f32x4 ag[4][2], al[4][2];
#pragma unroll
    for (int i = 0; i < 4; ++i)
#pragma unroll
        for (int j = 0; j < 2; ++j) { ag[i][j] = z0; al[i][j] = z0; }

    for (int k0 = 0; k0 < 1024; k0 += 64) {
#pragma unroll
        for (int c = 0; c < 4; ++c) {
            const int lin = c * 256 + tid;
            const int row = lin >> 3, col = (lin & 7) * 8;
            g2l16(A + (size_t)(m0 + row) * 1024 + k0 + col, (char*)As + lin * 16);
        }
#pragma unroll
        for (int c = 0; c < 2; ++c) {
            const int lin = c * 256 + tid;
            const int row = lin >> 3, col = (lin & 7) * 8;
            g2l16(Bg + (size_t)(n0 + row) * 1024 + k0 + col, (char*)Bgs + lin * 16);
        }
#pragma unroll
        for (int c = 0; c < 2; ++c) {
            const int lin = c * 256 + tid;
            const int row = lin >> 3, col = (lin & 7) * 8;
            g2l16(Bl + (size_t)(n0 + row) * 1024 + k0 + col, (char*)Bls + lin * 16);
        }
        __syncthreads();

        bf16x8 af[2][4], bg[2][2], bl[2][2];
#pragma unroll
        for (int kk = 0; kk < 2; ++kk) {
#pragma unroll
            for (int mi = 0; mi < 4; ++mi)
                af[kk][mi] = *(const bf16x8*)(As + (wr * 64 + mi * 16 + lr) * 64 +
                                              kk * 32 + lg * 8);
#pragma unroll
            for (int ni = 0; ni < 2; ++ni) {
                bg[kk][ni] = *(const bf16x8*)(Bgs + (wc * 32 + ni * 16 + lr) * 64 +
                                              kk * 32 + lg * 8);
                bl[kk][ni] = *(const bf16x8*)(Bls + (wc * 32 + ni * 16 + lr) * 64 +
                                              kk * 32 + lg * 8);
            }
        }
#pragma unroll
        for (int mi = 0; mi < 4; ++mi)
#pragma unroll
            for (int ni = 0; ni < 2; ++ni) {
#pragma unroll
                for (int kk = 0; kk < 2; ++kk) {
                    ag[mi][ni] = __builtin_amdgcn_mfma_f32_16x16x32_bf16(
                        af[kk][mi], bg[kk][ni], ag[mi][ni], 0, 0, 0);
                    al[mi][ni] = __builtin_amdgcn_mfma_f32_16x16x32_bf16(
                        af[kk][mi], bl[kk][ni], al[mi][ni], 0, 0, 0);
                }
            }
        __syncthreads();
    }

#pragma unroll
    for (int mi = 0; mi < 4; ++mi)
#pragma unroll
        for (int ni = 0; ni < 2; ++ni) {
            const int gc = n0 + wc * 32 + ni * 16 + lr;
            const int gr0 = m0 + wr * 64 + mi * 16 + lg * 4;
            const float b0 = bi0[gc], b1 = bi1[gc];
#pragma unroll
            for (int r = 0; r < 4; ++r) {
                const float x = ag[mi][ni][r] + b0;
                const float y = al[mi][ni][r] + b1;
                const float ge = 0.5f * x * (1.f + erff(x * 0.70710678118654752f));
                gout[(size_t)(gr0 + r) * 4096 + gc] = (bf16_t)(ge * y);
            }
        }
}

// ======  fused attention v9: pass B 2 tiles/barrier, 4 K+V tile-slots  ======
// 64KB LDS = 4 slots x 16KB (K 8KB + V 8KB). Barrier at top of each 2-tile
// iter proves all waves finished the previous iter -> slots (kt+2)%4,(kt+3)%4
// free to restage. Counted vmcnt: per-tile 2 loads + 4 stores per wave.
// Pass A unchanged (16 x 128-row K tiles in 3 x 16KB of the same array).
__global__ __launch_bounds__(512)
void attn_fused(const bf16_t* __restrict__ q, const bf16_t* __restrict__ k,
                const bf16_t* __restrict__ vT, float* __restrict__ attn,
                bf16_t* __restrict__ ctx) {
    __shared__ bf16_t lds[4 * 8192];   // 65536 B
    const int tid = threadIdx.x, lane = tid & 63, wave = tid >> 6;   // 8 waves
    const int lr = lane & 15, lg = lane >> 4;
    int blk = blockIdx.x;
    blk = (blk & 7) * 64 + (blk >> 3);       // XCD swizzle (512 % 8 == 0)
    const int qc = blk & 15, bh = blk >> 4;
    const int b = bh >> 4, h = bh & 15;
    const int q0 = qc * 128 + wave * 16;
    const size_t base = (size_t)b * (Ss * 1024) + h * 64;
    constexpr float SCL = 0.125f * 1.4426950408889634f;   // 1/sqrt(64) * log2(e)
    const f32x4 z0 = {0.f, 0.f, 0.f, 0.f};

    const int st_r8 = lane >> 3;
    const int st_c0 = (lane & 7) ^ (st_r8 & 3) ^ ((wave & 1) << 2);
    const int st_c0A = (lane & 7) ^ (st_r8 & 3);

    const bf16x8 aq0 = *(const bf16x8*)(q + base + (size_t)(q0 + lr) * 1024 + lg * 8);
    const bf16x8 aq1 = *(const bf16x8*)(q + base + (size_t)(q0 + lr) * 1024 + 32 + lg * 8);
    const bf16_t* kb = k + base;
    const bf16_t* vb_base = vT + ((size_t)bh * 64) * Ss;

#define STAGE_KA(kt_, buf_)                                                       \
    {                                                                             \
        g2l16(kb + (size_t)((kt_) * 128 + wave * 16 + st_r8) * 1024 + st_c0A * 8, \
              lds + (buf_) * 8192 + wave * 1024);                                 \
        g2l16(kb + (size_t)((kt_) * 128 + wave * 16 + 8 + st_r8) * 1024 +         \
                  (st_c0A ^ 4) * 8,                                               \
              lds + (buf_) * 8192 + wave * 1024 + 512);                           \
    }
// pass B: tile slot (kt_)&3: K at slot+0, V at slot+4096 (elems)
#define STAGE_K2(kt_)                                                             \
    g2l16(kb + (size_t)((kt_) * 64 + wave * 8 + st_r8) * 1024 + st_c0 * 8,        \
          lds + ((kt_) & 3) * 8192 + wave * 512);
#define STAGE_V2(kt_)                                                             \
    g2l16(vb_base + (size_t)(wave * 8 + st_r8) * Ss + (kt_) * 64 + st_c0 * 8,     \
          lds + ((kt_) & 3) * 8192 + 4096 + wave * 512);

    // ---- pass A: esum over 16 tiles of 128 k-rows ----
    f32x4 ea = z0, eb = z0;
    STAGE_KA(0, 0);
    STAGE_KA(1, 1);
    for (int kt = 0; kt < 16; ++kt) {
        const int buf = kt % 3;
        if (kt == 15) { WAITCNT(0); } else { WAITCNT(2); }
        SCHEDB();
        __builtin_amdgcn_s_barrier();
        SCHEDB();
        f32x4 sa[8];
        __builtin_amdgcn_s_setprio(1);
#pragma unroll
        for (int ct = 0; ct < 8; ++ct) {
            const int ar = ct * 16 + lr;
            const int hz = (ar & 3) | (((ar >> 3) & 1) << 2);
            bf16x8 k0 = *(const bf16x8*)&lds[buf * 8192 + ar * 64 + (lg ^ hz) * 8];
            bf16x8 k1 = *(const bf16x8*)&lds[buf * 8192 + ar * 64 + (((4 + lg) ^ hz)) * 8];
            sa[ct] = __builtin_amdgcn_mfma_f32_16x16x32_bf16(k0, aq0, z0, 0, 0, 0);
            sa[ct] = __builtin_amdgcn_mfma_f32_16x16x32_bf16(k1, aq1, sa[ct], 0, 0, 0);
        }
        __builtin_amdgcn_s_setprio(0);
#pragma unroll
        for (int r = 0; r < 4; ++r) {
            ea[r] += exp2f(sa[0][r] * SCL) + exp2f(sa[1][r] * SCL) +
                     exp2f(sa[2][r] * SCL) + exp2f(sa[3][r] * SCL);
            eb[r] += exp2f(sa[4][r] * SCL) + exp2f(sa[5][r] * SCL) +
                     exp2f(sa[6][r] * SCL) + exp2f(sa[7][r] * SCL);
        }
        if (kt + 2 < 16) STAGE_KA(kt + 2, (kt + 2) % 3);
    }
    float e = ((ea[0] + ea[1]) + (ea[2] + ea[3])) + ((eb[0] + eb[1]) + (eb[2] + eb[3]));
    e += __shfl_xor(e, 16);
    e += __shfl_xor(e, 32);
    const float invl = 1.f / e;

    f32x4 cacc[4];
#pragma unroll
    for (int nd = 0; nd < 4; ++nd) cacc[nd] = z0;

    float* attn_base = attn + ((size_t)bh * Ss + q0 + lr) * Ss;

    __builtin_amdgcn_s_barrier();   // all waves done reading pass-A buffers
    SCHEDB();

    // ---- pass B: 2 tiles per barrier ----
    STAGE_K2(0); STAGE_V2(0);
    STAGE_K2(1); STAGE_V2(1);
    for (int kt = 0; kt < 32; kt += 2) {
        __builtin_amdgcn_s_barrier();
        SCHEDB();
        if (kt + 2 < 32) {
            STAGE_K2(kt + 2); STAGE_V2(kt + 2);
            STAGE_K2(kt + 3); STAGE_V2(kt + 3);
        }
        if (kt == 0) { WAITCNT(4); }
        else if (kt == 30) { WAITCNT(8); }
        else { WAITCNT(12); }
        SCHEDB();
#pragma unroll
        for (int t = 0; t < 2; ++t) {
            const int ktt = kt + t;
            const int slot = (ktt & 3) * 8192;
#pragma unroll
            for (int kp = 0; kp < 2; ++kp) {
                bf16x8 pa;
                __builtin_amdgcn_s_setprio(1);
#pragma unroll
                for (int ch = 0; ch < 2; ++ch) {
                    const int pr = kp * 32 + (lr >> 2) * 8 + ch * 4 + (lr & 3);
                    const int hz = (pr & 3) | (((pr >> 3) & 1) << 2);
                    bf16x8 k0 = *(const bf16x8*)&lds[slot + pr * 64 + (lg ^ hz) * 8];
                    bf16x8 k1 = *(const bf16x8*)&lds[slot + pr * 64 + (((4 + lg) ^ hz)) * 8];
                    f32x4 sb = __builtin_amdgcn_mfma_f32_16x16x32_bf16(k0, aq0, z0, 0, 0, 0);
                    sb = __builtin_amdgcn_mfma_f32_16x16x32_bf16(k1, aq1, sb, 0, 0, 0);
                    float4 p;
                    p.x = exp2f(sb[0] * SCL) * invl;
                    p.y = exp2f(sb[1] * SCL) * invl;
                    p.z = exp2f(sb[2] * SCL) * invl;
                    p.w = exp2f(sb[3] * SCL) * invl;
                    *(float4*)(attn_base + ktt * 64 + kp * 32 + lg * 8 + ch * 4) = p;
                    pa[ch * 4 + 0] = (bf16_t)p.x;
                    pa[ch * 4 + 1] = (bf16_t)p.y;
                    pa[ch * 4 + 2] = (bf16_t)p.z;
                    pa[ch * 4 + 3] = (bf16_t)p.w;
                }
#pragma unroll
                for (int nd = 0; nd < 4; ++nd) {
                    const int vr = nd * 16 + lr;
                    const int hv = (vr & 3) | (((vr >> 3) & 1) << 2);
                    bf16x8 vb = *(const bf16x8*)&lds[slot + 4096 + vr * 64 +
                                                     (((kp * 4 + lg) ^ hv)) * 8];
                    cacc[nd] = __builtin_amdgcn_mfma_f32_16x16x32_bf16(pa, vb, cacc[nd], 0, 0, 0);
                }
                __builtin_amdgcn_s_setprio(0);
            }
        }
    }
#pragma unroll
    for (int nd = 0; nd < 4; ++nd)
#pragma unroll
        for (int r = 0; r < 4; ++r)
            ctx[((size_t)b * Ss + q0 + lg * 4 + r) * 1024 + h * 64 + nd * 16 + lr] =
                (bf16_t)cacc[nd][r];
#undef STAGE_KA
#undef STAGE_K2
#undef STAGE_V2
}

// =====================  launcher  =====================
extern "C" void kernel_launch(void* const* d_in, const int* in_sizes, int n_in,
                              void* d_out, int out_size, void* d_ws, size_t ws_size,
                              hipStream_t stream) {
    const float* inp  = (const float*)d_in[0];
    const float* wq   = (const float*)d_in[1];
    const float* bq   = (const float*)d_in[2];
    const float* wk   = (const float*)d_in[3];
    const float* bk   = (const float*)d_in[4];
    const float* wv   = (const float*)d_in[5];
    const float* bv   = (const float*)d_in[6];
    const float* wo   = (const float*)d_in[7];
    const float* bo   = (const float*)d_in[8];
    const float* ln1g = (const float*)d_in[9];
    const float* ln1b = (const float*)d_in[10];
    const float* wi0  = (const float*)d_in[11];
    const float* bi0  = (const float*)d_in[12];
    const float* wi1  = (const float*)d_in[13];
    const float* bi1  = (const float*)d_in[14];
    const float* wff  = (const float*)d_in[15];
    const float* bff  = (const float*)d_in[16];
    const float* ln2g = (const float*)d_in[17];
    const float* ln2b = (const float*)d_in[18];

    // ---- workspace layout (152 MiB envelope, time-disjoint reuse) ----
    const size_t M1 = 1u << 20;
    bf16_t* wsb  = (bf16_t*)d_ws;
    bf16_t* wqT  = wsb + 0 * M1;
    bf16_t* wkT  = wsb + 1 * M1;
    bf16_t* wvT  = wsb + 2 * M1;
    bf16_t* woT  = wsb + 3 * M1;
    bf16_t* wi0T = wsb + 4 * M1;
    bf16_t* wi1T = wsb + 8 * M1;
    bf16_t* wffT = wsb + 12 * M1;
    bf16_t* hbuf = wsb + 16 * M1;            // LN out; dead after geglu
    bf16_t* qbuf = wsb + 20 * M1;
    bf16_t* kbuf = wsb + 24 * M1;
    bf16_t* vTb  = wsb + 28 * M1;            // [B,H,DK,S]
    bf16_t* ctxb = wsb + 32 * M1;            // dead after WO
    float*  h1   = (float*)(wsb + 36 * M1);  // 4M f32 (36M..44M slots)
    bf16_t* gbuf = wsb + 44 * M1;            // geglu out (44M..60M)
    float*  part = (float*)(wsb + 20 * M1);  // splitK partials (20M..36M; qkv/ctx dead)
    float*  cb   = (float*)(wsb + 60 * M1);  // qkv bias concat (consumed step 2)

    float* out  = (float*)d_out;
    float* attn = out + (size_t)TOK * Dd;

    // 1) weights transpose + qkv bias concat + LN1, one launch (overlapped)
    prepass<<<16385 + TOK, 256, 0, stream>>>(wq, wk, wv, wo, wi0, wi1, wff,
                                             wqT, wkT, wvT, woT, wi0T, wi1T, wffT,
                                             bq, bk, bv, cb,
                                             inp, ln1g, ln1b, hbuf);

    // 2) fused QKV projection, 128x128 (768 blocks = 3/CU); v via LDS bounce
    gemm_t<128, 128, 3><<<dim3(24, 32), 256, 0, stream>>>(
        hbuf, wqT, cb, nullptr, qbuf, kbuf, vTb, TOK, 3072, 1024, 1024);

    // 3) fused attention (512 blocks x 8 waves)
    attn_fused<<<Bb * Hh * (Ss / 128), 512, 0, stream>>>(qbuf, kbuf, vTb, attn, ctxb);

    // 4) output projection + residual -> h1 (f32), 64x64 (1024 blocks)
    gemm_t<64, 64, 1><<<dim3(16, 64), 256, 0, stream>>>(
        ctxb, woT, bo, inp, h1, nullptr, nullptr, TOK, 1024, 1024, 1024);

    // 5) LN2
    ln_fwd<<<TOK, 256, 0, stream>>>(h1, ln2g, ln2b, hbuf);

    // 6) fused FFN-up + GeGLU -> gbuf (2048 blocks)
    gemm_geglu<<<dim3(64, 32), 256, 0, stream>>>(hbuf, wi0T, wi1T, bi0, bi1, gbuf);

    // 7) down projection 128x64, split-K=2 -> partials (1024 blocks = 4/CU)
    gemm_t<128, 64, 4><<<dim3(16, 32, 2), 256, 0, stream>>>(
        gbuf, wffT, bff, nullptr, part, nullptr, nullptr, TOK, 1024, 2048, 4096);

    // 8) reduce partials + bias + residual -> out
    reduce2<<<4096, 256, 0, stream>>>(part, h1, bff, out);
}

// Round 16
// 446.808 us; speedup vs baseline: 1.2862x; 1.0003x over previous
//
#include <hip/hip_runtime.h>
#include <hip/hip_bf16.h>
#include <cstdint>

#define DEV __device__ __forceinline__

typedef __bf16 bf16_t;
typedef __bf16 bf16x8 __attribute__((ext_vector_type(8)));
typedef __bf16 bf16x4 __attribute__((ext_vector_type(4)));
typedef float  f32x4  __attribute__((ext_vector_type(4)));

constexpr int Bb = 2, Ss = 2048, Dd = 1024, Hh = 16, DKk = 64, FFf = 4096;
constexpr int TOK = Bb * Ss;          // 4096 tokens
constexpr float LN_EPS = 1e-6f;

// ---- async global->LDS, 16B per lane (wave-uniform base + lane*16) ----
DEV void g2l16(const void* g, void* l) {
    __builtin_amdgcn_global_load_lds(
        (const __attribute__((address_space(1))) unsigned int*)g,
        (__attribute__((address_space(3))) unsigned int*)l, 16, 0, 0);
}

#define WAITCNT(N) asm volatile("s_waitcnt vmcnt(" #N ")" ::: "memory")
#define SCHEDB() __builtin_amdgcn_sched_barrier(0)

// ====  fused pre-pass: weights fp32->bf16 transposed + QKV bias + LN1  ======
__global__ __launch_bounds__(256)
void prepass(const float* __restrict__ wq, const float* __restrict__ wk,
             const float* __restrict__ wv, const float* __restrict__ wo,
             const float* __restrict__ wi0, const float* __restrict__ wi1,
             const float* __restrict__ wff,
             bf16_t* wqT, bf16_t* wkT, bf16_t* wvT, bf16_t* woT,
             bf16_t* wi0T, bf16_t* wi1T, bf16_t* wffT,
             const float* __restrict__ bq, const float* __restrict__ bk,
             const float* __restrict__ bv, float* __restrict__ cb,
             const float* __restrict__ x, const float* __restrict__ lg,
             const float* __restrict__ lb, bf16_t* __restrict__ lnout) {
    __shared__ float t[32][33];
    const int id = blockIdx.x;
    const int tid = threadIdx.x;
    if (id >= 16385) {                    // ---- LN1 row ----
        __shared__ float red[8];
        const int row = id - 16385;
        const float4 v = ((const float4*)(x + (size_t)row * Dd))[tid];
        float s  = v.x + v.y + v.z + v.w;
        float sq = v.x * v.x + v.y * v.y + v.z * v.z + v.w * v.w;
#pragma unroll
        for (int o = 32; o; o >>= 1) { s += __shfl_xor(s, o); sq += __shfl_xor(sq, o); }
        if ((tid & 63) == 0) { red[tid >> 6] = s; red[4 + (tid >> 6)] = sq; }
        __syncthreads();
        s  = red[0] + red[1] + red[2] + red[3];
        sq = red[4] + red[5] + red[6] + red[7];
        const float mean = s * (1.f / Dd);
        const float var  = sq * (1.f / Dd) - mean * mean;
        const float rs   = rsqrtf(var + LN_EPS);
        const float4 gv = ((const float4*)lg)[tid];
        const float4 bv2 = ((const float4*)lb)[tid];
        bf16x4 o4;
        o4[0] = (bf16_t)((v.x - mean) * rs * gv.x + bv2.x);
        o4[1] = (bf16_t)((v.y - mean) * rs * gv.y + bv2.y);
        o4[2] = (bf16_t)((v.z - mean) * rs * gv.z + bv2.z);
        o4[3] = (bf16_t)((v.w - mean) * rs * gv.w + bv2.w);
        ((bf16x4*)(lnout + (size_t)row * Dd))[tid] = o4;
        return;
    }
    if (id == 16384) {                    // ---- bias concat ----
#pragma unroll
        for (int i = 0; i < 4; ++i) {
            const int j = i * 256 + tid;
            cb[j] = bq[j]; cb[1024 + j] = bk[j]; cb[2048 + j] = bv[j];
        }
        return;
    }
    const float* src; bf16_t* dst; int K, N, tt;
    if (id < 4096) {
        const int w = id >> 10; tt = id & 1023; K = 1024; N = 1024;
        src = w == 0 ? wq : w == 1 ? wk : w == 2 ? wv : wo;
        dst = w == 0 ? wqT : w == 1 ? wkT : w == 2 ? wvT : woT;
    } else if (id < 12288) {
        const int w = (id - 4096) >> 12; tt = (id - 4096) & 4095; K = 1024; N = 4096;
        src = w ? wi1 : wi0; dst = w ? wi1T : wi0T;
    } else {
        tt = id - 12288; K = 4096; N = 1024;
        src = wff; dst = wffT;
    }
    const int ntn = N >> 5;
    const int n0 = (tt % ntn) * 32, k0 = (tt / ntn) * 32;
    const int tx = tid & 31, ty = tid >> 5;
#pragma unroll
    for (int i = 0; i < 4; ++i)
        t[ty + 8 * i][tx] = src[(size_t)(k0 + ty + 8 * i) * N + n0 + tx];
    __syncthreads();
#pragma unroll
    for (int i = 0; i < 4; ++i)
        dst[(size_t)(n0 + ty + 8 * i) * K + k0 + tx] = (bf16_t)t[tx][ty + 8 * i];
}

// =====================  LayerNorm fp32 -> bf16 (LN2)  =====================
__global__ __launch_bounds__(256)
void ln_fwd(const float* __restrict__ x, const float* __restrict__ g,
            const float* __restrict__ b, bf16_t* __restrict__ out) {
    __shared__ float red[8];
    const int row = blockIdx.x, tid = threadIdx.x;
    const float4 v = ((const float4*)(x + (size_t)row * Dd))[tid];
    float s  = v.x + v.y + v.z + v.w;
    float sq = v.x * v.x + v.y * v.y + v.z * v.z + v.w * v.w;
#pragma unroll
    for (int o = 32; o; o >>= 1) { s += __shfl_xor(s, o); sq += __shfl_xor(sq, o); }
    if ((tid & 63) == 0) { red[tid >> 6] = s; red[4 + (tid >> 6)] = sq; }
    __syncthreads();
    s  = red[0] + red[1] + red[2] + red[3];
    sq = red[4] + red[5] + red[6] + red[7];
    const float mean = s * (1.f / Dd);
    const float var  = sq * (1.f / Dd) - mean * mean;
    const float rs   = rsqrtf(var + LN_EPS);
    const float4 gv = ((const float4*)g)[tid];
    const float4 bv = ((const float4*)b)[tid];
    bf16x4 o4;
    o4[0] = (bf16_t)((v.x - mean) * rs * gv.x + bv.x);
    o4[1] = (bf16_t)((v.y - mean) * rs * gv.y + bv.y);
    o4[2] = (bf16_t)((v.z - mean) * rs * gv.z + bv.z);
    o4[3] = (bf16_t)((v.w - mean) * rs * gv.w + bv.w);
    ((bf16x4*)(out + (size_t)row * Dd))[tid] = o4;
}

// ---- shared GEMM epilogue (scalar paths) ----
template <int EPI>
DEV void gemm_epi(float val, int gr, int gc, int N, size_t zofs,
                  void* outp, void* out2, const float* resid) {
    if constexpr (EPI == 0) {
        ((bf16_t*)outp)[(size_t)gr * N + gc] = (bf16_t)val;
    } else if constexpr (EPI == 1) {
        const size_t idx = (size_t)gr * N + gc;
        ((float*)outp)[idx] = val + resid[idx];
    } else if constexpr (EPI == 4) {
        ((float*)outp)[zofs + (size_t)gr * N + gc] = val;   // split-K partial
    } else {
        const int sel = gc >> 10, col = gc & 1023;
        if (sel == 0) ((bf16_t*)outp)[(size_t)gr * 1024 + col] = (bf16_t)val;
        else          ((bf16_t*)out2)[(size_t)gr * 1024 + col] = (bf16_t)val;
    }
}

// =====================  GEMM: C = A[M,ld] @ Bt[N,ld]^T + bias  ==============
template <int BM, int BN, int EPI>
__global__ __launch_bounds__(256)
void gemm_t(const bf16_t* __restrict__ A, const bf16_t* __restrict__ Bt,
            const float* __restrict__ bias, const float* __restrict__ resid,
            void* __restrict__ outp, void* __restrict__ out2,
            void* __restrict__ out3, int M, int N, int K, int ld) {
    constexpr int WM = BM / 2, WN = BN / 2;
    constexpr int MI = WM / 16, NI = WN / 16;
    constexpr int CA = BM / 32, CB = BN / 32;
    __shared__ bf16_t sh[BM * 64 + BN * 64];
    bf16_t* As = sh;
    bf16_t* Bs = sh + BM * 64;
    const int tid = threadIdx.x;
    const int lane = tid & 63;
    const int wave = tid >> 6;
    const int wr = wave >> 1, wc = wave & 1;
    const int m0 = blockIdx.y * BM, n0 = blockIdx.x * BN;
    const int koff = blockIdx.z * K;
    const size_t zofs = (size_t)blockIdx.z * M * N;
    const int lr = lane & 15, lg = lane >> 4;

    const f32x4 z0 = {0.f, 0.f, 0.f, 0.f};
    f32x4 acc[MI][NI];
#pragma unroll
    for (int i = 0; i < MI; ++i)
#pragma unroll
        for (int j = 0; j < NI; ++j) acc[i][j] = z0;

    for (int k0 = 0; k0 < K; k0 += 64) {
#pragma unroll
        for (int c = 0; c < CA; ++c) {
            const int lin = c * 256 + tid;
            const int row = lin >> 3, col = (lin & 7) * 8;
            g2l16(A + (size_t)(m0 + row) * ld + koff + k0 + col, (char*)As + lin * 16);
        }
#pragma unroll
        for (int c = 0; c < CB; ++c) {
            const int lin = c * 256 + tid;
            const int row = lin >> 3, col = (lin & 7) * 8;
            g2l16(Bt + (size_t)(n0 + row) * ld + koff + k0 + col, (char*)Bs + lin * 16);
        }
        __syncthreads();

        bf16x8 af[2][MI], bw[2][NI];
#pragma unroll
        for (int kk = 0; kk < 2; ++kk)
#pragma unroll
            for (int mi = 0; mi < MI; ++mi)
                af[kk][mi] = *(const bf16x8*)(As + (wr * WM + mi * 16 + lr) * 64 +
                                              kk * 32 + lg * 8);
#pragma unroll
        for (int kk = 0; kk < 2; ++kk)
#pragma unroll
            for (int ni = 0; ni < NI; ++ni)
                bw[kk][ni] = *(const bf16x8*)(Bs + (wc * WN + ni * 16 + lr) * 64 +
                                              kk * 32 + lg * 8);
#pragma unroll
        for (int mi = 0; mi < MI; ++mi)
#pragma unroll
            for (int ni = 0; ni < NI; ++ni) {
                acc[mi][ni] = __builtin_amdgcn_mfma_f32_16x16x32_bf16(
                    af[0][mi], bw[0][ni], acc[mi][ni], 0, 0, 0);
                acc[mi][ni] = __builtin_amdgcn_mfma_f32_16x16x32_bf16(
                    af[1][mi], bw[1][ni], acc[mi][ni], 0, 0, 0);
            }
        __syncthreads();
    }

    if constexpr (EPI == 3) {
        if (n0 >= 2048 && BM == 128 && BN == 128) {
            // ---- v-block: LDS-bounce transpose, coalesced vT write ----
            bf16_t* tb = sh;
#pragma unroll
            for (int mi = 0; mi < MI; ++mi)
#pragma unroll
                for (int ni = 0; ni < NI; ++ni) {
                    const int cl = wc * WN + ni * 16 + lr;
                    const int rl0 = wr * WM + mi * 16 + lg * 4;
                    const float bvl = bias[n0 + cl];
#pragma unroll
                    for (int r = 0; r < 4; ++r)
                        tb[cl * 128 + rl0 + r] = (bf16_t)(acc[mi][ni][r] + bvl);
                }
            __syncthreads();
            const int bb = m0 >> 11, s0 = m0 & 2047;
            bf16_t* vout = (bf16_t*)out3 + ((size_t)bb << 21) + ((size_t)(n0 - 2048) << 11) + s0;
            const int cl = tid >> 4;
            const int sc = (tid & 15) * 8;
#pragma unroll
            for (int rnd = 0; rnd < 8; ++rnd) {
                const int c = rnd * 16 + cl;
                *(bf16x8*)(vout + ((size_t)c << 11) + sc) =
                    *(const bf16x8*)(tb + c * 128 + sc);
            }
            return;
        }
    }

#pragma unroll
    for (int mi = 0; mi < MI; ++mi)
#pragma unroll
        for (int ni = 0; ni < NI; ++ni) {
            const int gc = n0 + wc * WN + ni * 16 + lr;
            const int gr0 = m0 + wr * WM + mi * 16 + lg * 4;
            const float bvl = (EPI == 4) ? 0.f : bias[gc];
#pragma unroll
            for (int r = 0; r < 4; ++r)
                gemm_epi<EPI>(acc[mi][ni][r] + bvl, gr0 + r, gc, N, zofs,
                              outp, out2, resid);
        }
}

// =====================  split-K=2 reduce: out = p0+p1+bff+h1  ================
__global__ __launch_bounds__(256)
void reduce2(const float* __restrict__ part, const float* __restrict__ h1,
             const float* __restrict__ bff, float* __restrict__ out) {
    const int row = blockIdx.x, tid = threadIdx.x;
    const size_t idx = (size_t)row * 1024 + tid * 4;
    const float4 a = *(const float4*)(part + idx);
    const float4 b = *(const float4*)(part + (size_t)4096 * 1024 + idx);
    const float4 r = *(const float4*)(h1 + idx);
    const float4 bv = *(const float4*)(bff + tid * 4);
    float4 o;
    o.x = a.x + b.x + r.x + bv.x;
    o.y = a.y + b.y + r.y + bv.y;
    o.z = a.z + b.z + r.z + bv.z;
    o.w = a.w + b.w + r.w + bv.w;
    *(float4*)(out + idx) = o;
}

// =====================  fused FFN-up + GeGLU (unchanged)  ====================
__global__ __launch_bounds__(256)
void gemm_geglu(const bf16_t* __restrict__ A, const bf16_t* __restrict__ Bg,
                const bf16_t* __restrict__ Bl, const float* __restrict__ bi0,
                const float* __restrict__ bi1, bf16_t* __restrict__ gout) {
    __shared__ bf16_t As[128 * 64];
    __shared__ bf16_t Bgs[64 * 64];
    __shared__ bf16_t Bls[64 * 64];
    const int tid = threadIdx.x;
    const int lane = tid & 63;
    const int wave = tid >> 6;
    const int wr = wave >> 1, wc = wave & 1;
    const int m0 = blockIdx.y * 128, n0 = blockIdx.x * 64;
    const int lr = lane & 15, lg = lane >> 4;

    const f32x4 z0 = {0.f, 0.f, 0.f, 0.f};
    f32x4 ag[4][2], al[4][2];
#pragma unroll
    for (int i = 0; i < 4; ++i)
#pragma unroll
        for (int j = 0; j < 2; ++j) { ag[i][j] = z0; al[i][j] = z0; }

    for (int k0 = 0; k0 < 1024; k0 += 64) {
#pragma unroll
        for (int c = 0; c < 4; ++c) {
            const int lin = c * 256 + tid;
            const int row = lin >> 3, col = (lin & 7) * 8;
            g2l16(A + (size_t)(m0 + row) * 1024 + k0 + col, (char*)As + lin * 16);
        }
#pragma unroll
        for (int c = 0; c < 2; ++c) {
            const int lin = c * 256 + tid;
            const int row = lin >> 3, col = (lin & 7) * 8;
            g2l16(Bg + (size_t)(n0 + row) * 1024 + k0 + col, (char*)Bgs + lin * 16);
        }
#pragma unroll
        for (int c = 0; c < 2; ++c) {
            const int lin = c * 256 + tid;
            const int row = lin >> 3, col = (lin & 7) * 8;
            g2l16(Bl + (size_t)(n0 + row) * 1024 + k0 + col, (char*)Bls + lin * 16);
        }
        __syncthreads();

        bf16x8 af[2][4], bg[2][2], bl[2][2];
#pragma unroll
        for (int kk = 0; kk < 2; ++kk) {
#pragma unroll
            for (int mi = 0; mi < 4; ++mi)
                af[kk][mi] = *(const bf16x8*)(As + (wr * 64 + mi * 16 + lr) * 64 +
                                              kk * 32 + lg * 8);
#pragma unroll
            for (int ni = 0; ni < 2; ++ni) {
                bg[kk][ni] = *(const bf16x8*)(Bgs + (wc * 32 + ni * 16 + lr) * 64 +
                                              kk * 32 + lg * 8);
                bl[kk][ni] = *(const bf16x8*)(Bls + (wc * 32 + ni * 16 + lr) * 64 +
                                              kk * 32 + lg * 8);
            }
        }
#pragma unroll
        for (int mi = 0; mi < 4; ++mi)
#pragma unroll
            for (int ni = 0; ni < 2; ++ni) {
#pragma unroll
                for (int kk = 0; kk < 2; ++kk) {
                    ag[mi][ni] = __builtin_amdgcn_mfma_f32_16x16x32_bf16(
                        af[kk][mi], bg[kk][ni], ag[mi][ni], 0, 0, 0);
                    al[mi][ni] = __builtin_amdgcn_mfma_f32_16x16x32_bf16(
                        af[kk][mi], bl[kk][ni], al[mi][ni], 0, 0, 0);
                }
            }
        __syncthreads();
    }

#pragma unroll
    for (int mi = 0; mi < 4; ++mi)
#pragma unroll
        for (int ni = 0; ni < 2; ++ni) {
            const int gc = n0 + wc * 32 + ni * 16 + lr;
            const int gr0 = m0 + wr * 64 + mi * 16 + lg * 4;
            const float b0 = bi0[gc], b1 = bi1[gc];
#pragma unroll
            for (int r = 0; r < 4; ++r) {
                const float x = ag[mi][ni][r] + b0;
                const float y = al[mi][ni][r] + b1;
                const float ge = 0.5f * x * (1.f + erff(x * 0.70710678118654752f));
                gout[(size_t)(gr0 + r) * 4096 + gc] = (bf16_t)(ge * y);
            }
        }
}

// ======  fused attention v10: BOTH passes 2 tiles/barrier, 4 slots  =========
// 64KB LDS = 4 slots x 16KB. Pass A slot = one 128-row K tile; pass B slot =
// K(8KB) + V(8KB) 64-row pair. Barrier-at-top proves iter-1 consumed the
// slots being restaged; counted vmcnt keeps prefetch in flight.
__global__ __launch_bounds__(512)
void attn_fused(const bf16_t* __restrict__ q, const bf16_t* __restrict__ k,
                const bf16_t* __restrict__ vT, float* __restrict__ attn,
                bf16_t* __restrict__ ctx) {
    __shared__ bf16_t lds[4 * 8192];   // 65536 B
    const int tid = threadIdx.x, lane = tid & 63, wave = tid >> 6;   // 8 waves
    const int lr = lane & 15, lg = lane >> 4;
    int blk = blockIdx.x;
    blk = (blk & 7) * 64 + (blk >> 3);       // XCD swizzle (512 % 8 == 0)
    const int qc = blk & 15, bh = blk >> 4;
    const int b = bh >> 4, h = bh & 15;
    const int q0 = qc * 128 + wave * 16;
    const size_t base = (size_t)b * (Ss * 1024) + h * 64;
    constexpr float SCL = 0.125f * 1.4426950408889634f;   // 1/sqrt(64) * log2(e)
    const f32x4 z0 = {0.f, 0.f, 0.f, 0.f};

    const int st_r8 = lane >> 3;
    const int st_c0 = (lane & 7) ^ (st_r8 & 3) ^ ((wave & 1) << 2);
    const int st_c0A = (lane & 7) ^ (st_r8 & 3);

    const bf16x8 aq0 = *(const bf16x8*)(q + base + (size_t)(q0 + lr) * 1024 + lg * 8);
    const bf16x8 aq1 = *(const bf16x8*)(q + base + (size_t)(q0 + lr) * 1024 + 32 + lg * 8);
    const bf16_t* kb = k + base;
    const bf16_t* vb_base = vT + ((size_t)bh * 64) * Ss;

#define STAGE_KA(kt_)                                                             \
    {                                                                             \
        g2l16(kb + (size_t)((kt_) * 128 + wave * 16 + st_r8) * 1024 + st_c0A * 8, \
              lds + ((kt_) & 3) * 8192 + wave * 1024);                            \
        g2l16(kb + (size_t)((kt_) * 128 + wave * 16 + 8 + st_r8) * 1024 +         \
                  (st_c0A ^ 4) * 8,                                               \
              lds + ((kt_) & 3) * 8192 + wave * 1024 + 512);                      \
    }
#define STAGE_K2(kt_)                                                             \
    g2l16(kb + (size_t)((kt_) * 64 + wave * 8 + st_r8) * 1024 + st_c0 * 8,        \
          lds + ((kt_) & 3) * 8192 + wave * 512);
#define STAGE_V2(kt_)                                                             \
    g2l16(vb_base + (size_t)(wave * 8 + st_r8) * Ss + (kt_) * 64 + st_c0 * 8,     \
          lds + ((kt_) & 3) * 8192 + 4096 + wave * 512);

    // ---- pass A: esum over 16 x 128-row tiles, 2 tiles per barrier ----
    f32x4 ea = z0, eb = z0;
    STAGE_KA(0);
    STAGE_KA(1);
    for (int kt = 0; kt < 16; kt += 2) {
        __builtin_amdgcn_s_barrier();
        SCHEDB();
        if (kt + 2 < 16) {
            STAGE_KA(kt + 2);
            STAGE_KA(kt + 3);
            WAITCNT(4);
        } else {
            WAITCNT(0);
        }
        SCHEDB();
#pragma unroll
        for (int t = 0; t < 2; ++t) {
            const int slot = ((kt + t) & 3) * 8192;
            f32x4 sa[8];
            __builtin_amdgcn_s_setprio(1);
#pragma unroll
            for (int ct = 0; ct < 8; ++ct) {
                const int ar = ct * 16 + lr;
                const int hz = (ar & 3) | (((ar >> 3) & 1) << 2);
                bf16x8 k0 = *(const bf16x8*)&lds[slot + ar * 64 + (lg ^ hz) * 8];
                bf16x8 k1 = *(const bf16x8*)&lds[slot + ar * 64 + (((4 + lg) ^ hz)) * 8];
                sa[ct] = __builtin_amdgcn_mfma_f32_16x16x32_bf16(k0, aq0, z0, 0, 0, 0);
                sa[ct] = __builtin_amdgcn_mfma_f32_16x16x32_bf16(k1, aq1, sa[ct], 0, 0, 0);
            }
            __builtin_amdgcn_s_setprio(0);
#pragma unroll
            for (int r = 0; r < 4; ++r) {
                ea[r] += exp2f(sa[0][r] * SCL) + exp2f(sa[1][r] * SCL) +
                         exp2f(sa[2][r] * SCL) + exp2f(sa[3][r] * SCL);
                eb[r] += exp2f(sa[4][r] * SCL) + exp2f(sa[5][r] * SCL) +
                         exp2f(sa[6][r] * SCL) + exp2f(sa[7][r] * SCL);
            }
        }
    }
    float e = ((ea[0] + ea[1]) + (ea[2] + ea[3])) + ((eb[0] + eb[1]) + (eb[2] + eb[3]));
    e += __shfl_xor(e, 16);
    e += __shfl_xor(e, 32);
    const float invl = 1.f / e;

    f32x4 cacc[4];
#pragma unroll
    for (int nd = 0; nd < 4; ++nd) cacc[nd] = z0;

    float* attn_base = attn + ((size_t)bh * Ss + q0 + lr) * Ss;

    __builtin_amdgcn_s_barrier();   // all waves done reading pass-A buffers
    SCHEDB();

    // ---- pass B: 2 tiles per barrier (round-15 proven) ----
    STAGE_K2(0); STAGE_V2(0);
    STAGE_K2(1); STAGE_V2(1);
    for (int kt = 0; kt < 32; kt += 2) {
        __builtin_amdgcn_s_barrier();
        SCHEDB();
        if (kt + 2 < 32) {
            STAGE_K2(kt + 2); STAGE_V2(kt + 2);
            STAGE_K2(kt + 3); STAGE_V2(kt + 3);
        }
        if (kt == 0) { WAITCNT(4); }
        else if (kt == 30) { WAITCNT(8); }
        else { WAITCNT(12); }
        SCHEDB();
#pragma unroll
        for (int t = 0; t < 2; ++t) {
            const int ktt = kt + t;
            const int slot = (ktt & 3) * 8192;
#pragma unroll
            for (int kp = 0; kp < 2; ++kp) {
                bf16x8 pa;
                __builtin_amdgcn_s_setprio(1);
#pragma unroll
                for (int ch = 0; ch < 2; ++ch) {
                    const int pr = kp * 32 + (lr >> 2) * 8 + ch * 4 + (lr & 3);
                    const int hz = (pr & 3) | (((pr >> 3) & 1) << 2);
                    bf16x8 k0 = *(const bf16x8*)&lds[slot + pr * 64 + (lg ^ hz) * 8];
                    bf16x8 k1 = *(const bf16x8*)&lds[slot + pr * 64 + (((4 + lg) ^ hz)) * 8];
                    f32x4 sb = __builtin_amdgcn_mfma_f32_16x16x32_bf16(k0, aq0, z0, 0, 0, 0);
                    sb = __builtin_amdgcn_mfma_f32_16x16x32_bf16(k1, aq1, sb, 0, 0, 0);
                    float4 p;
                    p.x = exp2f(sb[0] * SCL) * invl;
                    p.y = exp2f(sb[1] * SCL) * invl;
                    p.z = exp2f(sb[2] * SCL) * invl;
                    p.w = exp2f(sb[3] * SCL) * invl;
                    *(float4*)(attn_base + ktt * 64 + kp * 32 + lg * 8 + ch * 4) = p;
                    pa[ch * 4 + 0] = (bf16_t)p.x;
                    pa[ch * 4 + 1] = (bf16_t)p.y;
                    pa[ch * 4 + 2] = (bf16_t)p.z;
                    pa[ch * 4 + 3] = (bf16_t)p.w;
                }
#pragma unroll
                for (int nd = 0; nd < 4; ++nd) {
                    const int vr = nd * 16 + lr;
                    const int hv = (vr & 3) | (((vr >> 3) & 1) << 2);
                    bf16x8 vb = *(const bf16x8*)&lds[slot + 4096 + vr * 64 +
                                                     (((kp * 4 + lg) ^ hv)) * 8];
                    cacc[nd] = __builtin_amdgcn_mfma_f32_16x16x32_bf16(pa, vb, cacc[nd], 0, 0, 0);
                }
                __builtin_amdgcn_s_setprio(0);
            }
        }
    }
#pragma unroll
    for (int nd = 0; nd < 4; ++nd)
#pragma unroll
        for (int r = 0; r < 4; ++r)
            ctx[((size_t)b * Ss + q0 + lg * 4 + r) * 1024 + h * 64 + nd * 16 + lr] =
                (bf16_t)cacc[nd][r];
#undef STAGE_KA
#undef STAGE_K2
#undef STAGE_V2
}

// =====================  launcher  =====================
extern "C" void kernel_launch(void* const* d_in, const int* in_sizes, int n_in,
                              void* d_out, int out_size, void* d_ws, size_t ws_size,
                              hipStream_t stream) {
    const float* inp  = (const float*)d_in[0];
    const float* wq   = (const float*)d_in[1];
    const float* bq   = (const float*)d_in[2];
    const float* wk   = (const float*)d_in[3];
    const float* bk   = (const float*)d_in[4];
    const float* wv   = (const float*)d_in[5];
    const float* bv   = (const float*)d_in[6];
    const float* wo   = (const float*)d_in[7];
    const float* bo   = (const float*)d_in[8];
    const float* ln1g = (const float*)d_in[9];
    const float* ln1b = (const float*)d_in[10];
    const float* wi0  = (const float*)d_in[11];
    const float* bi0  = (const float*)d_in[12];
    const float* wi1  = (const float*)d_in[13];
    const float* bi1  = (const float*)d_in[14];
    const float* wff  = (const float*)d_in[15];
    const float* bff  = (const float*)d_in[16];
    const float* ln2g = (const float*)d_in[17];
    const float* ln2b = (const float*)d_in[18];

    // ---- workspace layout (152 MiB envelope, time-disjoint reuse) ----
    const size_t M1 = 1u << 20;
    bf16_t* wsb  = (bf16_t*)d_ws;
    bf16_t* wqT  = wsb + 0 * M1;
    bf16_t* wkT  = wsb + 1 * M1;
    bf16_t* wvT  = wsb + 2 * M1;
    bf16_t* woT  = wsb + 3 * M1;
    bf16_t* wi0T = wsb + 4 * M1;
    bf16_t* wi1T = wsb + 8 * M1;
    bf16_t* wffT = wsb + 12 * M1;
    bf16_t* hbuf = wsb + 16 * M1;            // LN out; dead after geglu
    bf16_t* qbuf = wsb + 20 * M1;
    bf16_t* kbuf = wsb + 24 * M1;
    bf16_t* vTb  = wsb + 28 * M1;            // [B,H,DK,S]
    bf16_t* ctxb = wsb + 32 * M1;            // dead after WO
    float*  h1   = (float*)(wsb + 36 * M1);  // 4M f32 (36M..44M slots)
    bf16_t* gbuf = wsb + 44 * M1;            // geglu out (44M..60M)
    float*  part = (float*)(wsb + 20 * M1);  // splitK partials (20M..36M; qkv/ctx dead)
    float*  cb   = (float*)(wsb + 60 * M1);  // qkv bias concat (consumed step 2)

    float* out  = (float*)d_out;
    float* attn = out + (size_t)TOK * Dd;

    // 1) weights transpose + qkv bias concat + LN1, one launch (overlapped)
    prepass<<<16385 + TOK, 256, 0, stream>>>(wq, wk, wv, wo, wi0, wi1, wff,
                                             wqT, wkT, wvT, woT, wi0T, wi1T, wffT,
                                             bq, bk, bv, cb,
                                             inp, ln1g, ln1b, hbuf);

    // 2) fused QKV projection, 128x128 (768 blocks = 3/CU); v via LDS bounce
    gemm_t<128, 128, 3><<<dim3(24, 32), 256, 0, stream>>>(
        hbuf, wqT, cb, nullptr, qbuf, kbuf, vTb, TOK, 3072, 1024, 1024);

    // 3) fused attention (512 blocks x 8 waves)
    attn_fused<<<Bb * Hh * (Ss / 128), 512, 0, stream>>>(qbuf, kbuf, vTb, attn, ctxb);

    // 4) output projection + residual -> h1 (f32), 64x64 (1024 blocks)
    gemm_t<64, 64, 1><<<dim3(16, 64), 256, 0, stream>>>(
        ctxb, woT, bo, inp, h1, nullptr, nullptr, TOK, 1024, 1024, 1024);

    // 5) LN2
    ln_fwd<<<TOK, 256, 0, stream>>>(h1, ln2g, ln2b, hbuf);

    // 6) fused FFN-up + GeGLU -> gbuf (2048 blocks)
    gemm_geglu<<<dim3(64, 32), 256, 0, stream>>>(hbuf, wi0T, wi1T, bi0, bi1, gbuf);

    // 7) down projection 128x64, split-K=2 -> partials (1024 blocks = 4/CU)
    gemm_t<128, 64, 4><<<dim3(16, 32, 2), 256, 0, stream>>>(
        gbuf, wffT, bff, nullptr, part, nullptr, nullptr, TOK, 1024, 2048, 4096);

    // 8) reduce partials + bias + residual -> out
    reduce2<<<4096, 256, 0, stream>>>(part, h1, bff, out);
}